// Round 1
// baseline (1514.037 us; speedup 1.0000x reference)
//
#include <hip/hip_runtime.h>
#include <hip/hip_bf16.h>

#define Sq 1024
#define Dm 1024
#define Hh 16
#define KVh 4
#define HDim 64
#define Ee 8
#define Ff 1024
#define EPS 1e-5f

// ---------------- rmsnorm: out = x * rsqrt(mean(x^2)+eps) * w ----------------
__global__ void rmsnorm_k(const float* __restrict__ in, const float* __restrict__ w,
                          float* __restrict__ out, int W) {
  int s = blockIdx.x;
  int t = threadIdx.x;
  __shared__ float red[256];
  const float* row = in + (size_t)s * W;
  float local = 0.f;
  for (int i = t; i < W; i += 256) { float v = row[i]; local += v * v; }
  red[t] = local; __syncthreads();
  for (int o = 128; o > 0; o >>= 1) { if (t < o) red[t] += red[t + o]; __syncthreads(); }
  float scale = rsqrtf(red[0] / W + EPS);
  for (int i = t; i < W; i += 256) out[(size_t)s * W + i] = row[i] * scale * w[i];
}

// ------------- fused rmsnorm + RoPE (in-place), W = 1024 (q) or 256 (k) -------------
__global__ void normrope_k(float* __restrict__ buf, const float* __restrict__ w,
                           const float* __restrict__ cosb, const float* __restrict__ sinb,
                           int W) {
  int s = blockIdx.x, t = threadIdx.x;
  __shared__ float rowb[1024];
  __shared__ float red[256];
  float* row = buf + (size_t)s * W;
  float local = 0.f;
  for (int i = t; i < W; i += 256) { float v = row[i]; rowb[i] = v; local += v * v; }
  red[t] = local; __syncthreads();
  for (int o = 128; o > 0; o >>= 1) { if (t < o) red[t] += red[t + o]; __syncthreads(); }
  float scale = rsqrtf(red[0] / W + EPS);
  for (int i = t; i < W; i += 256) {
    int hd = i & 63;
    int pair = (hd < 32) ? i + 32 : i - 32;
    float xv = rowb[i] * scale * w[i];
    float pv = rowb[pair] * scale * w[pair];
    float rot = (hd < 32) ? -pv : pv;
    row[i] = xv * cosb[s * 64 + hd] + rot * sinb[s * 64 + hd];
  }
}

// ---------------- dense NN GEMM: C = A[M,K] @ B[K,N] (+ add), 64x64 tile ----------------
__global__ void gemm_nn_k(const float* __restrict__ A, const float* __restrict__ B,
                          const float* __restrict__ add, float* __restrict__ C,
                          int M, int N, int K) {
  __shared__ float As[64][33];
  __shared__ float Bs[32][65];
  int tx = threadIdx.x, ty = threadIdx.y, tid = ty * 16 + tx;
  int row0 = blockIdx.y * 64, col0 = blockIdx.x * 64;
  float acc[4][4] = {};
  int lr = tid >> 5, lc = tid & 31;   // A loads: 8 rows apart
  int br = tid >> 6, bc = tid & 63;   // B loads: 4 rows apart
  for (int k0 = 0; k0 < K; k0 += 32) {
#pragma unroll
    for (int i = 0; i < 8; i++)
      As[lr + 8 * i][lc] = A[(size_t)(row0 + lr + 8 * i) * K + k0 + lc];
#pragma unroll
    for (int i = 0; i < 8; i++)
      Bs[br + 4 * i][bc] = B[(size_t)(k0 + br + 4 * i) * N + col0 + bc];
    __syncthreads();
#pragma unroll
    for (int kk = 0; kk < 32; kk++) {
      float a[4], b[4];
#pragma unroll
      for (int i = 0; i < 4; i++) a[i] = As[ty + 16 * i][kk];
#pragma unroll
      for (int j = 0; j < 4; j++) b[j] = Bs[kk][tx + 16 * j];
#pragma unroll
      for (int i = 0; i < 4; i++)
#pragma unroll
        for (int j = 0; j < 4; j++) acc[i][j] += a[i] * b[j];
    }
    __syncthreads();
  }
#pragma unroll
  for (int i = 0; i < 4; i++) {
    int r = row0 + ty + 16 * i;
#pragma unroll
    for (int j = 0; j < 4; j++) {
      int c = col0 + tx + 16 * j;
      float v = acc[i][j];
      if (add) v += add[(size_t)r * N + c];
      C[(size_t)r * N + c] = v;
    }
  }
}

// ---------------- causal attention, one block per (q_row, head) ----------------
__global__ void attn_k(const float* __restrict__ q, const float* __restrict__ kb,
                       const float* __restrict__ vb, float* __restrict__ o) {
  int qi = blockIdx.x, h = blockIdx.y, t = threadIdx.x;
  int kvh = h >> 2;
  __shared__ float sc[1024];
  __shared__ float qv[64];
  __shared__ float red[256];
  __shared__ float part[4][64];
  if (t < 64) qv[t] = q[(size_t)qi * 1024 + h * 64 + t];
  __syncthreads();
  int nk = qi + 1;
  float lmax = -1e30f;
  for (int k = t; k < nk; k += 256) {
    const float* kr = kb + (size_t)k * 256 + kvh * 64;
    float d = 0.f;
#pragma unroll
    for (int j = 0; j < 64; j++) d += qv[j] * kr[j];
    d *= 0.125f;
    sc[k] = d; lmax = fmaxf(lmax, d);
  }
  red[t] = lmax; __syncthreads();
  for (int oo = 128; oo > 0; oo >>= 1) { if (t < oo) red[t] = fmaxf(red[t], red[t + oo]); __syncthreads(); }
  float m = red[0];
  __syncthreads();
  float lsum = 0.f;
  for (int k = t; k < nk; k += 256) { float e = __expf(sc[k] - m); sc[k] = e; lsum += e; }
  red[t] = lsum; __syncthreads();
  for (int oo = 128; oo > 0; oo >>= 1) { if (t < oo) red[t] += red[t + oo]; __syncthreads(); }
  float inv = 1.f / red[0];
  int g = t >> 6, d = t & 63;
  float p = 0.f;
  for (int k = g; k < nk; k += 4) p += sc[k] * vb[(size_t)k * 256 + kvh * 64 + d];
  part[g][d] = p; __syncthreads();
  if (t < 64) {
    float v = (part[0][t] + part[1][t] + part[2][t] + part[3][t]) * inv;
    o[(size_t)qi * 1024 + h * 64 + t] = v;
  }
}

// ---------------- routing: softmax(h2 @ w_gate) + top-2 ----------------
__global__ void route_k(const float* __restrict__ h2, const float* __restrict__ wg,
                        int* __restrict__ ti, float* __restrict__ tp) {
  int s = blockIdx.x, lane = threadIdx.x;  // 64 threads = 1 wave
  float acc[8] = {0, 0, 0, 0, 0, 0, 0, 0};
  for (int dd = lane; dd < 1024; dd += 64) {
    float hv = h2[(size_t)s * 1024 + dd];
    const float* wr = wg + (size_t)dd * 8;
#pragma unroll
    for (int e = 0; e < 8; e++) acc[e] += hv * wr[e];
  }
#pragma unroll
  for (int off = 32; off > 0; off >>= 1) {
#pragma unroll
    for (int e = 0; e < 8; e++) acc[e] += __shfl_down(acc[e], off);
  }
  if (lane == 0) {
    float m = acc[0];
    for (int e = 1; e < 8; e++) m = fmaxf(m, acc[e]);
    float ex[8], sum = 0.f;
    for (int e = 0; e < 8; e++) { ex[e] = __expf(acc[e] - m); sum += ex[e]; }
    float inv = 1.f / sum;
    int i1 = 0;
    for (int e = 1; e < 8; e++) if (ex[e] > ex[i1]) i1 = e;
    int i2 = (i1 == 0) ? 1 : 0;
    for (int e = 0; e < 8; e++) if (e != i1 && ex[e] > ex[i2]) i2 = e;
    ti[2 * s] = i1; ti[2 * s + 1] = i2;
    tp[2 * s] = ex[i1] * inv; tp[2 * s + 1] = ex[i2] * inv;
  }
}

// ---------------- scatter tokens into per-expert lists ----------------
__global__ void scatter_k(const int* __restrict__ ti, int* __restrict__ cnt,
                          int* __restrict__ list) {
  int t = blockIdx.x * 256 + threadIdx.x;
  if (t < 2048) {
    int e = ti[t];
    int pos = atomicAdd(&cnt[e], 1);
    list[e * 1024 + pos] = t;  // t = s*2 + slot
  }
}

// ------------- gathered NT GEMM: hidden[s2,f] = silu(h2@gate_e^T) * (h2@up_e^T) -------------
__global__ void ffn_upgate_k(const float* __restrict__ h2, const float* __restrict__ up,
                             const float* __restrict__ gate, const int* __restrict__ cnt,
                             const int* __restrict__ list, float* __restrict__ hidden) {
  int e = blockIdx.z;
  int n = cnt[e];
  int ri0 = blockIdx.y * 64;
  if (ri0 >= n) return;
  int col0 = blockIdx.x * 64;
  __shared__ float As[64][33];
  __shared__ float Bu[64][33];
  __shared__ float Bg[64][33];
  int tx = threadIdx.x, ty = threadIdx.y, tid = ty * 16 + tx;
  int lr = tid >> 5, lc = tid & 31;
  const float* upe = up + (size_t)e * Ff * Dm;
  const float* gte = gate + (size_t)e * Ff * Dm;
  float au[4][4] = {}, ag[4][4] = {};
  for (int k0 = 0; k0 < Dm; k0 += 32) {
#pragma unroll
    for (int i = 0; i < 8; i++) {
      int r = lr + 8 * i;
      int gi = ri0 + r;
      float av = 0.f;
      if (gi < n) { int s2 = list[e * 1024 + gi]; av = h2[(size_t)(s2 >> 1) * Dm + k0 + lc]; }
      As[r][lc] = av;
      Bu[r][lc] = upe[(size_t)(col0 + r) * Dm + k0 + lc];
      Bg[r][lc] = gte[(size_t)(col0 + r) * Dm + k0 + lc];
    }
    __syncthreads();
#pragma unroll
    for (int kk = 0; kk < 32; kk++) {
      float a[4], u[4], g[4];
#pragma unroll
      for (int i = 0; i < 4; i++) a[i] = As[ty + 16 * i][kk];
#pragma unroll
      for (int j = 0; j < 4; j++) { u[j] = Bu[tx + 16 * j][kk]; g[j] = Bg[tx + 16 * j][kk]; }
#pragma unroll
      for (int i = 0; i < 4; i++)
#pragma unroll
        for (int j = 0; j < 4; j++) { au[i][j] += a[i] * u[j]; ag[i][j] += a[i] * g[j]; }
    }
    __syncthreads();
  }
#pragma unroll
  for (int i = 0; i < 4; i++) {
    int gi = ri0 + ty + 16 * i;
    if (gi >= n) continue;
    int s2 = list[e * 1024 + gi];
#pragma unroll
    for (int j = 0; j < 4; j++) {
      int f = col0 + tx + 16 * j;
      float gv = ag[i][j];
      float sil = gv / (1.f + __expf(-gv));
      hidden[(size_t)s2 * Ff + f] = sil * au[i][j];
    }
  }
}

// ------------- gathered NT GEMM: dbuf[s2,d] = prob[s2] * (hidden[s2] @ down_e^T) -------------
__global__ void ffn_down_k(const float* __restrict__ hidden, const float* __restrict__ dp,
                           const int* __restrict__ cnt, const int* __restrict__ list,
                           const float* __restrict__ tp, float* __restrict__ dbuf) {
  int e = blockIdx.z;
  int n = cnt[e];
  int ri0 = blockIdx.y * 64;
  if (ri0 >= n) return;
  int col0 = blockIdx.x * 64;
  __shared__ float As[64][33];
  __shared__ float Bs[64][33];
  int tx = threadIdx.x, ty = threadIdx.y, tid = ty * 16 + tx;
  int lr = tid >> 5, lc = tid & 31;
  const float* dpe = dp + (size_t)e * Dm * Ff;
  float acc[4][4] = {};
  for (int k0 = 0; k0 < Ff; k0 += 32) {
#pragma unroll
    for (int i = 0; i < 8; i++) {
      int r = lr + 8 * i;
      int gi = ri0 + r;
      float av = 0.f;
      if (gi < n) { int s2 = list[e * 1024 + gi]; av = hidden[(size_t)s2 * Ff + k0 + lc]; }
      As[r][lc] = av;
      Bs[r][lc] = dpe[(size_t)(col0 + r) * Ff + k0 + lc];
    }
    __syncthreads();
#pragma unroll
    for (int kk = 0; kk < 32; kk++) {
      float a[4], b[4];
#pragma unroll
      for (int i = 0; i < 4; i++) a[i] = As[ty + 16 * i][kk];
#pragma unroll
      for (int j = 0; j < 4; j++) b[j] = Bs[tx + 16 * j][kk];
#pragma unroll
      for (int i = 0; i < 4; i++)
#pragma unroll
        for (int j = 0; j < 4; j++) acc[i][j] += a[i] * b[j];
    }
    __syncthreads();
  }
#pragma unroll
  for (int i = 0; i < 4; i++) {
    int gi = ri0 + ty + 16 * i;
    if (gi >= n) continue;
    int s2 = list[e * 1024 + gi];
    float p = tp[s2];
#pragma unroll
    for (int j = 0; j < 4; j++) {
      int c = col0 + tx + 16 * j;
      dbuf[(size_t)s2 * Dm + c] = p * acc[i][j];
    }
  }
}

// ---------------- final: out = x2 + dbuf[s,0] + dbuf[s,1] ----------------
__global__ void final_add_k(const float* __restrict__ x2, const float* __restrict__ dbuf,
                            float* __restrict__ out) {
  int s = blockIdx.x, t = threadIdx.x;
  for (int i = t; i < 1024; i += 256) {
    size_t o = (size_t)s * 1024 + i;
    out[o] = x2[o] + dbuf[(size_t)(2 * s) * 1024 + i] + dbuf[(size_t)(2 * s + 1) * 1024 + i];
  }
}

extern "C" void kernel_launch(void* const* d_in, const int* in_sizes, int n_in,
                              void* d_out, int out_size, void* d_ws, size_t ws_size,
                              hipStream_t stream) {
  const float* x    = (const float*)d_in[0];
  const float* cosb = (const float*)d_in[1];
  const float* sinb = (const float*)d_in[2];
  // d_in[3] = mask (always causal tril -> implicit), d_in[4] = layer_idx (unused)
  const float* w_in = (const float*)d_in[5];
  const float* wq   = (const float*)d_in[6];
  const float* wk   = (const float*)d_in[7];
  const float* wv   = (const float*)d_in[8];
  const float* wo   = (const float*)d_in[9];
  const float* w_qn = (const float*)d_in[10];
  const float* w_kn = (const float*)d_in[11];
  const float* w_pn = (const float*)d_in[12];
  const float* wg   = (const float*)d_in[13];
  const float* up   = (const float*)d_in[14];
  const float* gate = (const float*)d_in[15];
  const float* dp   = (const float*)d_in[16];
  float* out = (float*)d_out;

  char* w = (char*)d_ws;
  float* h      = (float*)w; w += (size_t)Sq * Dm * 4;
  float* qb     = (float*)w; w += (size_t)Sq * Dm * 4;
  float* kb     = (float*)w; w += (size_t)Sq * 256 * 4;
  float* vb     = (float*)w; w += (size_t)Sq * 256 * 4;
  float* attn   = (float*)w; w += (size_t)Sq * Dm * 4;
  float* x2     = (float*)w; w += (size_t)Sq * Dm * 4;
  float* h2     = (float*)w; w += (size_t)Sq * Dm * 4;
  float* hidden = (float*)w; w += (size_t)Sq * 2 * Ff * 4;
  float* dbuf   = (float*)w; w += (size_t)Sq * 2 * Dm * 4;
  float* tp     = (float*)w; w += 2048 * 4;
  int* ti       = (int*)w;   w += 2048 * 4;
  int* cnt      = (int*)w;   w += 64 * 4;
  int* list     = (int*)w;   w += 8192 * 4;

  hipMemsetAsync(cnt, 0, 8 * sizeof(int), stream);

  rmsnorm_k<<<Sq, 256, 0, stream>>>(x, w_in, h, Dm);
  gemm_nn_k<<<dim3(16, 16), dim3(16, 16), 0, stream>>>(h, wq, nullptr, qb, Sq, Dm, Dm);
  gemm_nn_k<<<dim3(4, 16), dim3(16, 16), 0, stream>>>(h, wk, nullptr, kb, Sq, 256, Dm);
  gemm_nn_k<<<dim3(4, 16), dim3(16, 16), 0, stream>>>(h, wv, nullptr, vb, Sq, 256, Dm);
  normrope_k<<<Sq, 256, 0, stream>>>(qb, w_qn, cosb, sinb, Dm);
  normrope_k<<<Sq, 256, 0, stream>>>(kb, w_kn, cosb, sinb, 256);
  attn_k<<<dim3(Sq, Hh), 256, 0, stream>>>(qb, kb, vb, attn);
  gemm_nn_k<<<dim3(16, 16), dim3(16, 16), 0, stream>>>(attn, wo, x, x2, Sq, Dm, Dm);
  rmsnorm_k<<<Sq, 256, 0, stream>>>(x2, w_pn, h2, Dm);
  route_k<<<Sq, 64, 0, stream>>>(h2, wg, ti, tp);
  scatter_k<<<8, 256, 0, stream>>>(ti, cnt, list);
  ffn_upgate_k<<<dim3(16, 16, 8), dim3(16, 16), 0, stream>>>(h2, up, gate, cnt, list, hidden);
  ffn_down_k<<<dim3(16, 16, 8), dim3(16, 16), 0, stream>>>(hidden, dp, cnt, list, tp, dbuf);
  final_add_k<<<Sq, 256, 0, stream>>>(x2, dbuf, out);
}

// Round 3
// 430.397 us; speedup vs baseline: 3.5178x; 3.5178x over previous
//
#include <hip/hip_runtime.h>
#include <hip/hip_bf16.h>

#define Sq 1024
#define Dm 1024
#define Hh 16
#define EPS 1e-5f

typedef __attribute__((ext_vector_type(8))) short short8;
typedef __attribute__((ext_vector_type(4))) short short4v;
typedef __attribute__((ext_vector_type(4))) float f32x4;

static __device__ __forceinline__ short f2bf(float f) {
  __hip_bfloat16 h = __float2bfloat16(f);
  return *reinterpret_cast<short*>(&h);
}

// ---------------- transpose + cast: in fp32 [R][C] -> out bf16 [C][R] ----------------
__global__ void transpose_cast_k(const float* __restrict__ in, __hip_bfloat16* __restrict__ outT,
                                 int R, int Cc) {
  __shared__ float t[32][33];
  int c0 = blockIdx.x * 32, r0 = blockIdx.y * 32;
  int tx = threadIdx.x, ty = threadIdx.y;
#pragma unroll
  for (int i = 0; i < 32; i += 8)
    t[ty + i][tx] = in[(size_t)(r0 + ty + i) * Cc + c0 + tx];
  __syncthreads();
#pragma unroll
  for (int i = 0; i < 32; i += 8)
    outT[(size_t)(c0 + ty + i) * R + r0 + tx] = __float2bfloat16(t[tx][ty + i]);
}

// ---------------- rmsnorm -> bf16 ----------------
__global__ void rmsnorm_b16_k(const float* __restrict__ in, const float* __restrict__ w,
                              __hip_bfloat16* __restrict__ outb) {
  int s = blockIdx.x, t = threadIdx.x;
  __shared__ float red[256];
  const float* row = in + (size_t)s * Dm;
  float local = 0.f;
  for (int i = t; i < Dm; i += 256) { float v = row[i]; local += v * v; }
  red[t] = local; __syncthreads();
  for (int o = 128; o > 0; o >>= 1) { if (t < o) red[t] += red[t + o]; __syncthreads(); }
  float scale = rsqrtf(red[0] / Dm + EPS);
  for (int i = t; i < Dm; i += 256)
    outb[(size_t)s * Dm + i] = __float2bfloat16(row[i] * scale * w[i]);
}

// ---------------- rmsnorm -> fp32 + bf16 ----------------
__global__ void rmsnorm_dual_k(const float* __restrict__ in, const float* __restrict__ w,
                               float* __restrict__ outf, __hip_bfloat16* __restrict__ outb) {
  int s = blockIdx.x, t = threadIdx.x;
  __shared__ float red[256];
  const float* row = in + (size_t)s * Dm;
  float local = 0.f;
  for (int i = t; i < Dm; i += 256) { float v = row[i]; local += v * v; }
  red[t] = local; __syncthreads();
  for (int o = 128; o > 0; o >>= 1) { if (t < o) red[t] += red[t + o]; __syncthreads(); }
  float scale = rsqrtf(red[0] / Dm + EPS);
  for (int i = t; i < Dm; i += 256) {
    float v = row[i] * scale * w[i];
    outf[(size_t)s * Dm + i] = v;
    outb[(size_t)s * Dm + i] = __float2bfloat16(v);
  }
}

// ---------------- fused rmsnorm + RoPE -> bf16 ----------------
__global__ void normrope_b16_k(const float* __restrict__ in, const float* __restrict__ w,
                               const float* __restrict__ cosb, const float* __restrict__ sinb,
                               __hip_bfloat16* __restrict__ outb, int W) {
  int s = blockIdx.x, t = threadIdx.x;
  __shared__ float rowb[1024];
  __shared__ float red[256];
  const float* row = in + (size_t)s * W;
  float local = 0.f;
  for (int i = t; i < W; i += 256) { float v = row[i]; rowb[i] = v; local += v * v; }
  red[t] = local; __syncthreads();
  for (int o = 128; o > 0; o >>= 1) { if (t < o) red[t] += red[t + o]; __syncthreads(); }
  float scale = rsqrtf(red[0] / W + EPS);
  for (int i = t; i < W; i += 256) {
    int hd = i & 63;
    int pair = (hd < 32) ? i + 32 : i - 32;
    float xv = rowb[i] * scale * w[i];
    float pv = rowb[pair] * scale * w[pair];
    float rot = (hd < 32) ? -pv : pv;
    outb[(size_t)s * W + i] = __float2bfloat16(xv * cosb[s * 64 + hd] + rot * sinb[s * 64 + hd]);
  }
}

// ---------------- dense NT GEMM: C[M,N] = A[M,K](bf16) @ Bt[N,K](bf16)^T (+add) ----------------
__global__ __launch_bounds__(256) void gemm_nt_k(
    const __hip_bfloat16* __restrict__ A, const __hip_bfloat16* __restrict__ Bt,
    const float* __restrict__ add, float* __restrict__ C, int M, int N, int K) {
  __shared__ unsigned short As[64][72];
  __shared__ unsigned short Bs[64][72];
  int tid = threadIdx.x, lane = tid & 63, wid = tid >> 6;
  int l15 = lane & 15, lg = lane >> 4;
  int wr = (wid >> 1) * 32, wc = (wid & 1) * 32;
  int row0 = blockIdx.y * 64, col0 = blockIdx.x * 64;
  int sr = tid >> 2, sk = (tid & 3) * 16;
  const __hip_bfloat16* Ar = A + (size_t)(row0 + sr) * K + sk;
  const __hip_bfloat16* Br = Bt + (size_t)(col0 + sr) * K + sk;
  f32x4 zero4 = {0.f, 0.f, 0.f, 0.f};
  f32x4 acc[2][2];
#pragma unroll
  for (int i = 0; i < 2; i++)
#pragma unroll
    for (int j = 0; j < 2; j++) acc[i][j] = zero4;
  for (int k0 = 0; k0 < K; k0 += 64) {
    *(short8*)&As[sr][sk]     = *(const short8*)(Ar + k0);
    *(short8*)&As[sr][sk + 8] = *(const short8*)(Ar + k0 + 8);
    *(short8*)&Bs[sr][sk]     = *(const short8*)(Br + k0);
    *(short8*)&Bs[sr][sk + 8] = *(const short8*)(Br + k0 + 8);
    __syncthreads();
#pragma unroll
    for (int ks = 0; ks < 2; ks++) {
      short8 af[2], bf[2];
#pragma unroll
      for (int i = 0; i < 2; i++) af[i] = *(const short8*)&As[wr + i * 16 + l15][ks * 32 + lg * 8];
#pragma unroll
      for (int j = 0; j < 2; j++) bf[j] = *(const short8*)&Bs[wc + j * 16 + l15][ks * 32 + lg * 8];
#pragma unroll
      for (int i = 0; i < 2; i++)
#pragma unroll
        for (int j = 0; j < 2; j++)
          acc[i][j] = __builtin_amdgcn_mfma_f32_16x16x32_bf16(af[i], bf[j], acc[i][j], 0, 0, 0);
    }
    __syncthreads();
  }
#pragma unroll
  for (int i = 0; i < 2; i++)
#pragma unroll
    for (int r = 0; r < 4; r++) {
      int row = row0 + wr + i * 16 + lg * 4 + r;
#pragma unroll
      for (int j = 0; j < 2; j++) {
        int col = col0 + wc + j * 16 + l15;
        float v = acc[i][j][r];
        if (add) v += add[(size_t)row * N + col];
        C[(size_t)row * N + col] = v;
      }
    }
}

// ---------------- flash attention: block = (64 q-rows, head), 4 waves x 16 rows ----------------
__global__ __launch_bounds__(256) void attn_flash_k(
    const __hip_bfloat16* __restrict__ qb16, const __hip_bfloat16* __restrict__ kb16,
    const __hip_bfloat16* __restrict__ vbT, __hip_bfloat16* __restrict__ attnb) {
  __shared__ unsigned short Kl[32][72];     // 32 kv tokens x 64 dims
  __shared__ unsigned short Vt[64][40];     // 64 dims x 32 kv tokens
  __shared__ unsigned short Pl[4][16][40];  // per-wave P: 16 q x 32 kv
  int h = blockIdx.y, kvh = h >> 2;
  int q0 = blockIdx.x * 64;
  int tid = threadIdx.x, lane = tid & 63, wid = tid >> 6;
  int l15 = lane & 15, lg = lane >> 4;
  int qr0 = q0 + wid * 16;
  int q_lane = qr0 + l15;

  short8 bq[2];
  const __hip_bfloat16* qrow = qb16 + (size_t)(qr0 + l15) * Dm + h * 64;
  bq[0] = *(const short8*)(qrow + lg * 8);
  bq[1] = *(const short8*)(qrow + 32 + lg * 8);

  f32x4 zero4 = {0.f, 0.f, 0.f, 0.f};
  f32x4 oacc[4];
#pragma unroll
  for (int j = 0; j < 4; j++) oacc[j] = zero4;
  float m_run = -1e30f, lsum = 0.f;

  int nt = q0 / 32 + 2;
  int s_r = tid >> 3, s_off = (tid & 7) * 8;   // K staging
  int s_dd = tid >> 2, s_c = (tid & 3) * 8;    // V staging
  for (int t = 0; t < nt; t++) {
    int kv0 = t * 32;
    *(short8*)&Kl[s_r][s_off] = *(const short8*)(kb16 + (size_t)(kv0 + s_r) * 256 + kvh * 64 + s_off);
    *(short8*)&Vt[s_dd][s_c] = *(const short8*)(vbT + (size_t)(kvh * 64 + s_dd) * Sq + kv0 + s_c);
    __syncthreads();

    // S^T = K . Q^T  (col = q = l15, row = kv = lg*4+r)
    f32x4 sacc[2];
#pragma unroll
    for (int kvg = 0; kvg < 2; kvg++) {
      short8 ak0 = *(const short8*)&Kl[kvg * 16 + l15][lg * 8];
      short8 ak1 = *(const short8*)&Kl[kvg * 16 + l15][32 + lg * 8];
      f32x4 sa = __builtin_amdgcn_mfma_f32_16x16x32_bf16(ak0, bq[0], zero4, 0, 0, 0);
      sa = __builtin_amdgcn_mfma_f32_16x16x32_bf16(ak1, bq[1], sa, 0, 0, 0);
      sacc[kvg] = sa;
    }
    float s[8];
    float tmax = -1e30f;
#pragma unroll
    for (int kvg = 0; kvg < 2; kvg++)
#pragma unroll
      for (int r = 0; r < 4; r++) {
        int kv_abs = kv0 + kvg * 16 + lg * 4 + r;
        float v = sacc[kvg][r] * 0.125f;
        if (kv_abs > q_lane) v = -1e30f;
        s[kvg * 4 + r] = v;
        tmax = fmaxf(tmax, v);
      }
    tmax = fmaxf(tmax, __shfl_xor(tmax, 16));
    tmax = fmaxf(tmax, __shfl_xor(tmax, 32));
    float m_new = fmaxf(m_run, tmax);
    float corr = __expf(m_run - m_new);
    float psum = 0.f;
#pragma unroll
    for (int i = 0; i < 8; i++) { float p = __expf(s[i] - m_new); s[i] = p; psum += p; }
    psum += __shfl_xor(psum, 16);
    psum += __shfl_xor(psum, 32);
    lsum = lsum * corr + psum;
    m_run = m_new;
    // rescale O (rows q' = lg*4+r need corr from lane q')
    float c4[4];
#pragma unroll
    for (int r = 0; r < 4; r++) c4[r] = __shfl(corr, lg * 4 + r);
#pragma unroll
    for (int j = 0; j < 4; j++)
#pragma unroll
      for (int r = 0; r < 4; r++) oacc[j][r] *= c4[r];
    // P -> bf16 LDS (A-frag layout), then PV
#pragma unroll
    for (int kvg = 0; kvg < 2; kvg++) {
      short4v p4;
#pragma unroll
      for (int r = 0; r < 4; r++) p4[r] = f2bf(s[kvg * 4 + r]);
      *(short4v*)&Pl[wid][l15][kvg * 16 + lg * 4] = p4;
    }
    short8 pa = *(const short8*)&Pl[wid][l15][lg * 8];
#pragma unroll
    for (int j = 0; j < 4; j++) {
      short8 vb = *(const short8*)&Vt[j * 16 + l15][lg * 8];
      oacc[j] = __builtin_amdgcn_mfma_f32_16x16x32_bf16(pa, vb, oacc[j], 0, 0, 0);
    }
    __syncthreads();
  }
  float inv = 1.f / lsum;
  float c4[4];
#pragma unroll
  for (int r = 0; r < 4; r++) c4[r] = __shfl(inv, lg * 4 + r);
#pragma unroll
  for (int j = 0; j < 4; j++)
#pragma unroll
    for (int r = 0; r < 4; r++) {
      int row = qr0 + lg * 4 + r;
      int col = h * 64 + j * 16 + l15;
      attnb[(size_t)row * Dm + col] = __float2bfloat16(oacc[j][r] * c4[r]);
    }
}

// ---------------- routing (fp32) ----------------
__global__ void route_k(const float* __restrict__ h2, const float* __restrict__ wg,
                        int* __restrict__ ti, float* __restrict__ tp) {
  int s = blockIdx.x, lane = threadIdx.x;
  float acc[8] = {0, 0, 0, 0, 0, 0, 0, 0};
  for (int dd = lane; dd < 1024; dd += 64) {
    float hv = h2[(size_t)s * 1024 + dd];
    const float* wr = wg + (size_t)dd * 8;
#pragma unroll
    for (int e = 0; e < 8; e++) acc[e] += hv * wr[e];
  }
#pragma unroll
  for (int off = 32; off > 0; off >>= 1) {
#pragma unroll
    for (int e = 0; e < 8; e++) acc[e] += __shfl_down(acc[e], off);
  }
  if (lane == 0) {
    float m = acc[0];
    for (int e = 1; e < 8; e++) m = fmaxf(m, acc[e]);
    float ex[8], sum = 0.f;
    for (int e = 0; e < 8; e++) { ex[e] = __expf(acc[e] - m); sum += ex[e]; }
    float inv = 1.f / sum;
    int i1 = 0;
    for (int e = 1; e < 8; e++) if (ex[e] > ex[i1]) i1 = e;
    int i2 = (i1 == 0) ? 1 : 0;
    for (int e = 0; e < 8; e++) if (e != i1 && ex[e] > ex[i2]) i2 = e;
    ti[2 * s] = i1; ti[2 * s + 1] = i2;
    tp[2 * s] = ex[i1] * inv; tp[2 * s + 1] = ex[i2] * inv;
  }
}

__global__ void scatter_k(const int* __restrict__ ti, int* __restrict__ cnt,
                          int* __restrict__ list) {
  int t = blockIdx.x * 256 + threadIdx.x;
  if (t < 2048) {
    int e = ti[t];
    int pos = atomicAdd(&cnt[e], 1);
    list[e * 1024 + pos] = t;  // t = s*2 + slot
  }
}

// ---------------- MoE up/gate: hidden[s2,f] = silu(h2@gate_e^T) * (h2@up_e^T), bf16 out ----------------
__global__ __launch_bounds__(256) void moe_upgate_k(
    const __hip_bfloat16* __restrict__ h2b, const float* __restrict__ up,
    const float* __restrict__ gate, const int* __restrict__ cnt,
    const int* __restrict__ list, __hip_bfloat16* __restrict__ hidden) {
  int e = blockIdx.z;
  int n = cnt[e];
  int ri0 = blockIdx.y * 64;
  if (ri0 >= n) return;
  __shared__ unsigned short As[64][72];
  __shared__ unsigned short Bu[64][72];
  __shared__ unsigned short Bg[64][72];
  int tid = threadIdx.x, lane = tid & 63, wid = tid >> 6;
  int l15 = lane & 15, lg = lane >> 4;
  int wr = (wid >> 1) * 32, wc = (wid & 1) * 32;
  int col0 = blockIdx.x * 64;
  int sr = tid >> 2, sk = (tid & 3) * 16;
  int gi = ri0 + sr;
  bool av = gi < n;
  int arow = av ? (list[e * 1024 + gi] >> 1) : 0;
  const float* upe = up + (size_t)e * 1024 * 1024 + (size_t)(col0 + sr) * 1024 + sk;
  const float* gte = gate + (size_t)e * 1024 * 1024 + (size_t)(col0 + sr) * 1024 + sk;
  const __hip_bfloat16* Ar = h2b + (size_t)arow * 1024 + sk;
  f32x4 zero4 = {0.f, 0.f, 0.f, 0.f};
  f32x4 aU[2][2], aG[2][2];
#pragma unroll
  for (int i = 0; i < 2; i++)
#pragma unroll
    for (int j = 0; j < 2; j++) { aU[i][j] = zero4; aG[i][j] = zero4; }
  for (int k0 = 0; k0 < 1024; k0 += 64) {
#pragma unroll
    for (int half = 0; half < 2; half++) {
      int kk = sk + half * 8;
      short8 a8 = {};
      if (av) a8 = *(const short8*)(Ar + k0 + half * 8);
      *(short8*)&As[sr][kk] = a8;
      const float* pu = upe + k0 + half * 8;
      const float* pg = gte + k0 + half * 8;
      short8 ub, gb;
#pragma unroll
      for (int q = 0; q < 8; q++) { ub[q] = f2bf(pu[q]); gb[q] = f2bf(pg[q]); }
      *(short8*)&Bu[sr][kk] = ub;
      *(short8*)&Bg[sr][kk] = gb;
    }
    __syncthreads();
#pragma unroll
    for (int ks = 0; ks < 2; ks++) {
      short8 af[2], bu[2], bg[2];
#pragma unroll
      for (int i = 0; i < 2; i++) af[i] = *(const short8*)&As[wr + i * 16 + l15][ks * 32 + lg * 8];
#pragma unroll
      for (int j = 0; j < 2; j++) {
        bu[j] = *(const short8*)&Bu[wc + j * 16 + l15][ks * 32 + lg * 8];
        bg[j] = *(const short8*)&Bg[wc + j * 16 + l15][ks * 32 + lg * 8];
      }
#pragma unroll
      for (int i = 0; i < 2; i++)
#pragma unroll
        for (int j = 0; j < 2; j++) {
          aU[i][j] = __builtin_amdgcn_mfma_f32_16x16x32_bf16(af[i], bu[j], aU[i][j], 0, 0, 0);
          aG[i][j] = __builtin_amdgcn_mfma_f32_16x16x32_bf16(af[i], bg[j], aG[i][j], 0, 0, 0);
        }
    }
    __syncthreads();
  }
#pragma unroll
  for (int i = 0; i < 2; i++)
#pragma unroll
    for (int r = 0; r < 4; r++) {
      int gi2 = ri0 + wr + i * 16 + lg * 4 + r;
      if (gi2 < n) {
        int s2 = list[e * 1024 + gi2];
#pragma unroll
        for (int j = 0; j < 2; j++) {
          int col = col0 + wc + j * 16 + l15;
          float g = aG[i][j][r], u = aU[i][j][r];
          float sil = g / (1.f + __expf(-g));
          hidden[(size_t)s2 * 1024 + col] = __float2bfloat16(sil * u);
        }
      }
    }
}

// ---------------- MoE down: dbuf[s2,d] = tp[s2] * (hidden[s2] @ down_e^T) ----------------
__global__ __launch_bounds__(256) void moe_down_k(
    const __hip_bfloat16* __restrict__ hidden, const float* __restrict__ dp,
    const int* __restrict__ cnt, const int* __restrict__ list,
    const float* __restrict__ tp, float* __restrict__ dbuf) {
  int e = blockIdx.z;
  int n = cnt[e];
  int ri0 = blockIdx.y * 64;
  if (ri0 >= n) return;
  __shared__ unsigned short As[64][72];
  __shared__ unsigned short Bs[64][72];
  int tid = threadIdx.x, lane = tid & 63, wid = tid >> 6;
  int l15 = lane & 15, lg = lane >> 4;
  int wr = (wid >> 1) * 32, wc = (wid & 1) * 32;
  int col0 = blockIdx.x * 64;
  int sr = tid >> 2, sk = (tid & 3) * 16;
  int gi = ri0 + sr;
  bool av = gi < n;
  int arow = av ? list[e * 1024 + gi] : 0;
  const float* dpe = dp + (size_t)e * 1024 * 1024 + (size_t)(col0 + sr) * 1024 + sk;
  const __hip_bfloat16* Ar = hidden + (size_t)arow * 1024 + sk;
  f32x4 zero4 = {0.f, 0.f, 0.f, 0.f};
  f32x4 acc[2][2];
#pragma unroll
  for (int i = 0; i < 2; i++)
#pragma unroll
    for (int j = 0; j < 2; j++) acc[i][j] = zero4;
  for (int k0 = 0; k0 < 1024; k0 += 64) {
#pragma unroll
    for (int half = 0; half < 2; half++) {
      int kk = sk + half * 8;
      short8 a8 = {};
      if (av) a8 = *(const short8*)(Ar + k0 + half * 8);
      *(short8*)&As[sr][kk] = a8;
      const float* pb = dpe + k0 + half * 8;
      short8 bb;
#pragma unroll
      for (int q = 0; q < 8; q++) bb[q] = f2bf(pb[q]);
      *(short8*)&Bs[sr][kk] = bb;
    }
    __syncthreads();
#pragma unroll
    for (int ks = 0; ks < 2; ks++) {
      short8 af[2], bf[2];
#pragma unroll
      for (int i = 0; i < 2; i++) af[i] = *(const short8*)&As[wr + i * 16 + l15][ks * 32 + lg * 8];
#pragma unroll
      for (int j = 0; j < 2; j++) bf[j] = *(const short8*)&Bs[wc + j * 16 + l15][ks * 32 + lg * 8];
#pragma unroll
      for (int i = 0; i < 2; i++)
#pragma unroll
        for (int j = 0; j < 2; j++)
          acc[i][j] = __builtin_amdgcn_mfma_f32_16x16x32_bf16(af[i], bf[j], acc[i][j], 0, 0, 0);
    }
    __syncthreads();
  }
#pragma unroll
  for (int i = 0; i < 2; i++)
#pragma unroll
    for (int r = 0; r < 4; r++) {
      int gi2 = ri0 + wr + i * 16 + lg * 4 + r;
      if (gi2 < n) {
        int s2 = list[e * 1024 + gi2];
        float p = tp[s2];
#pragma unroll
        for (int j = 0; j < 2; j++) {
          int col = col0 + wc + j * 16 + l15;
          dbuf[(size_t)s2 * 1024 + col] = p * acc[i][j][r];
        }
      }
    }
}

__global__ void final_add_k(const float* __restrict__ x2, const float* __restrict__ dbuf,
                            float* __restrict__ out) {
  int s = blockIdx.x, t = threadIdx.x;
  for (int i = t; i < 1024; i += 256) {
    size_t o = (size_t)s * 1024 + i;
    out[o] = x2[o] + dbuf[(size_t)(2 * s) * 1024 + i] + dbuf[(size_t)(2 * s + 1) * 1024 + i];
  }
}

extern "C" void kernel_launch(void* const* d_in, const int* in_sizes, int n_in,
                              void* d_out, int out_size, void* d_ws, size_t ws_size,
                              hipStream_t stream) {
  const float* x    = (const float*)d_in[0];
  const float* cosb = (const float*)d_in[1];
  const float* sinb = (const float*)d_in[2];
  const float* w_in = (const float*)d_in[5];
  const float* wq   = (const float*)d_in[6];
  const float* wk   = (const float*)d_in[7];
  const float* wv   = (const float*)d_in[8];
  const float* wo   = (const float*)d_in[9];
  const float* w_qn = (const float*)d_in[10];
  const float* w_kn = (const float*)d_in[11];
  const float* w_pn = (const float*)d_in[12];
  const float* wg   = (const float*)d_in[13];
  const float* up   = (const float*)d_in[14];
  const float* gate = (const float*)d_in[15];
  const float* dp   = (const float*)d_in[16];
  float* out = (float*)d_out;

  char* w = (char*)d_ws;
  const size_t MB = 1024 * 1024;
  __hip_bfloat16* hb    = (__hip_bfloat16*)w; w += 2 * MB;
  __hip_bfloat16* woT   = (__hip_bfloat16*)w; w += 2 * MB;
  // ---- dbuf alias region: qb(4) + kbf(1) + vbf(1) + wqT(2) = 8MB ----
  float* qb             = (float*)w;          w += 4 * MB;
  float* kbf            = (float*)w;          w += 1 * MB;
  float* vbf            = (float*)w;          w += 1 * MB;
  __hip_bfloat16* wqT   = (__hip_bfloat16*)w; w += 2 * MB;
  // -------------------------------------------------------------------
  __hip_bfloat16* wkT   = (__hip_bfloat16*)w; w += MB / 2;
  __hip_bfloat16* wvT   = (__hip_bfloat16*)w; w += MB / 2;
  __hip_bfloat16* qb16  = (__hip_bfloat16*)w; w += 2 * MB;
  __hip_bfloat16* kb16  = (__hip_bfloat16*)w; w += MB / 2;
  __hip_bfloat16* vbT   = (__hip_bfloat16*)w; w += MB / 2;
  __hip_bfloat16* attnb = (__hip_bfloat16*)w; w += 2 * MB;
  float* x2             = (float*)w;          w += 4 * MB;
  float* h2f            = (float*)w;          w += 4 * MB;
  __hip_bfloat16* h2b   = (__hip_bfloat16*)w; w += 2 * MB;
  __hip_bfloat16* hidden= (__hip_bfloat16*)w; w += 4 * MB;
  float* tp             = (float*)w;          w += 2048 * 4;
  int* ti               = (int*)w;            w += 2048 * 4;
  int* cnt              = (int*)w;            w += 64 * 4;
  int* list             = (int*)w;            w += 8192 * 4;
  float* dbuf = qb;  // 8MB alias (qb/kbf/vbf/wqT all dead by MoE-down time)

  hipMemsetAsync(cnt, 0, 8 * sizeof(int), stream);

  transpose_cast_k<<<dim3(32, 32), dim3(32, 8), 0, stream>>>(wq, wqT, 1024, 1024);
  transpose_cast_k<<<dim3(8, 32),  dim3(32, 8), 0, stream>>>(wk, wkT, 1024, 256);
  transpose_cast_k<<<dim3(8, 32),  dim3(32, 8), 0, stream>>>(wv, wvT, 1024, 256);
  transpose_cast_k<<<dim3(32, 32), dim3(32, 8), 0, stream>>>(wo, woT, 1024, 1024);

  rmsnorm_b16_k<<<Sq, 256, 0, stream>>>(x, w_in, hb);
  gemm_nt_k<<<dim3(16, 16), 256, 0, stream>>>(hb, wqT, nullptr, qb, 1024, 1024, 1024);
  gemm_nt_k<<<dim3(4, 16),  256, 0, stream>>>(hb, wkT, nullptr, kbf, 1024, 256, 1024);
  gemm_nt_k<<<dim3(4, 16),  256, 0, stream>>>(hb, wvT, nullptr, vbf, 1024, 256, 1024);

  normrope_b16_k<<<Sq, 256, 0, stream>>>(qb, w_qn, cosb, sinb, qb16, 1024);
  normrope_b16_k<<<Sq, 256, 0, stream>>>(kbf, w_kn, cosb, sinb, kb16, 256);
  transpose_cast_k<<<dim3(8, 32), dim3(32, 8), 0, stream>>>(vbf, vbT, 1024, 256);

  attn_flash_k<<<dim3(16, 16), 256, 0, stream>>>(qb16, kb16, vbT, attnb);
  gemm_nt_k<<<dim3(16, 16), 256, 0, stream>>>(attnb, woT, x, x2, 1024, 1024, 1024);

  rmsnorm_dual_k<<<Sq, 256, 0, stream>>>(x2, w_pn, h2f, h2b);
  route_k<<<Sq, 64, 0, stream>>>(h2f, wg, ti, tp);
  scatter_k<<<8, 256, 0, stream>>>(ti, cnt, list);
  moe_upgate_k<<<dim3(16, 16, 8), 256, 0, stream>>>(h2b, up, gate, cnt, list, hidden);
  moe_down_k<<<dim3(16, 16, 8), 256, 0, stream>>>(hidden, dp, cnt, list, tp, dbuf);
  final_add_k<<<Sq, 256, 0, stream>>>(x2, dbuf, out);
}

// Round 4
// 363.419 us; speedup vs baseline: 4.1661x; 1.1843x over previous
//
#include <hip/hip_runtime.h>
#include <hip/hip_bf16.h>

#define Sq 1024
#define Dm 1024
#define Hh 16
#define EPS 1e-5f

typedef __attribute__((ext_vector_type(8))) short short8;
typedef __attribute__((ext_vector_type(4))) short short4v;
typedef __attribute__((ext_vector_type(4))) float f32x4;

static __device__ __forceinline__ short f2bf(float f) {
  __hip_bfloat16 h = __float2bfloat16(f);
  return *reinterpret_cast<short*>(&h);
}

// ---------------- transpose + cast: in fp32 [R][C] -> out bf16 [C][R] ----------------
__global__ void transpose_cast_k(const float* __restrict__ in, __hip_bfloat16* __restrict__ outT,
                                 int R, int Cc) {
  __shared__ float t[32][33];
  int c0 = blockIdx.x * 32, r0 = blockIdx.y * 32;
  int tx = threadIdx.x, ty = threadIdx.y;
#pragma unroll
  for (int i = 0; i < 32; i += 8)
    t[ty + i][tx] = in[(size_t)(r0 + ty + i) * Cc + c0 + tx];
  __syncthreads();
#pragma unroll
  for (int i = 0; i < 32; i += 8)
    outT[(size_t)(c0 + ty + i) * R + r0 + tx] = __float2bfloat16(t[tx][ty + i]);
}

// ---------------- rmsnorm -> bf16 (row=1024, one f32x4 per thread) ----------------
__global__ void rmsnorm_b16_k(const float* __restrict__ in, const float* __restrict__ w,
                              __hip_bfloat16* __restrict__ outb) {
  int s = blockIdx.x, t = threadIdx.x;
  __shared__ float wsum[4];
  f32x4 v = *(const f32x4*)(in + (size_t)s * Dm + t * 4);
  float local = v[0] * v[0] + v[1] * v[1] + v[2] * v[2] + v[3] * v[3];
#pragma unroll
  for (int off = 32; off > 0; off >>= 1) local += __shfl_xor(local, off);
  if ((t & 63) == 0) wsum[t >> 6] = local;
  __syncthreads();
  float scale = rsqrtf((wsum[0] + wsum[1] + wsum[2] + wsum[3]) * (1.f / Dm) + EPS);
  f32x4 wv = *(const f32x4*)(w + t * 4);
  short4v o;
#pragma unroll
  for (int r = 0; r < 4; r++) o[r] = f2bf(v[r] * scale * wv[r]);
  *(short4v*)((unsigned short*)outb + (size_t)s * Dm + t * 4) = o;
}

// ---------------- rmsnorm -> fp32 + bf16 ----------------
__global__ void rmsnorm_dual_k(const float* __restrict__ in, const float* __restrict__ w,
                               float* __restrict__ outf, __hip_bfloat16* __restrict__ outb) {
  int s = blockIdx.x, t = threadIdx.x;
  __shared__ float wsum[4];
  f32x4 v = *(const f32x4*)(in + (size_t)s * Dm + t * 4);
  float local = v[0] * v[0] + v[1] * v[1] + v[2] * v[2] + v[3] * v[3];
#pragma unroll
  for (int off = 32; off > 0; off >>= 1) local += __shfl_xor(local, off);
  if ((t & 63) == 0) wsum[t >> 6] = local;
  __syncthreads();
  float scale = rsqrtf((wsum[0] + wsum[1] + wsum[2] + wsum[3]) * (1.f / Dm) + EPS);
  f32x4 wv = *(const f32x4*)(w + t * 4);
  f32x4 of;
  short4v o;
#pragma unroll
  for (int r = 0; r < 4; r++) { of[r] = v[r] * scale * wv[r]; o[r] = f2bf(of[r]); }
  *(f32x4*)(outf + (size_t)s * Dm + t * 4) = of;
  *(short4v*)((unsigned short*)outb + (size_t)s * Dm + t * 4) = o;
}

// ---------------- fused rmsnorm + RoPE -> bf16 (vectorized) ----------------
__global__ void normrope_b16_k(const float* __restrict__ in, const float* __restrict__ w,
                               const float* __restrict__ cosb, const float* __restrict__ sinb,
                               __hip_bfloat16* __restrict__ outb, int W) {
  int s = blockIdx.x, t = threadIdx.x;
  __shared__ float rowb[1024];
  __shared__ float wsum[4];
  const float* row = in + (size_t)s * W;
  bool act = t * 4 < W;
  f32x4 v = {};
  float local = 0.f;
  if (act) {
    v = *(const f32x4*)(row + t * 4);
    *(f32x4*)&rowb[t * 4] = v;
    local = v[0] * v[0] + v[1] * v[1] + v[2] * v[2] + v[3] * v[3];
  }
#pragma unroll
  for (int off = 32; off > 0; off >>= 1) local += __shfl_xor(local, off);
  if ((t & 63) == 0) wsum[t >> 6] = local;
  __syncthreads();
  if (!act) return;
  float scale = rsqrtf((wsum[0] + wsum[1] + wsum[2] + wsum[3]) / W + EPS);
  int i0 = t * 4, hd = i0 & 63;
  int pair0 = (hd < 32) ? i0 + 32 : i0 - 32;
  f32x4 pv = *(const f32x4*)&rowb[pair0];
  f32x4 wv = *(const f32x4*)(w + i0);
  f32x4 wp = *(const f32x4*)(w + pair0);
  float sgn = (hd < 32) ? -1.f : 1.f;
  short4v o;
#pragma unroll
  for (int r = 0; r < 4; r++) {
    float c = cosb[s * 64 + hd + r], si = sinb[s * 64 + hd + r];
    o[r] = f2bf(v[r] * scale * wv[r] * c + sgn * pv[r] * scale * wp[r] * si);
  }
  *(short4v*)((unsigned short*)outb + (size_t)s * W + i0) = o;
}

// ---------------- dense NT GEMM: C[M,N] = A[M,K](bf16) @ Bt[N,K](bf16)^T (+add) ----------------
__global__ __launch_bounds__(256) void gemm_nt_k(
    const __hip_bfloat16* __restrict__ A, const __hip_bfloat16* __restrict__ Bt,
    const float* __restrict__ add, float* __restrict__ C, int M, int N, int K) {
  __shared__ unsigned short As[64][72];
  __shared__ unsigned short Bs[64][72];
  int tid = threadIdx.x, lane = tid & 63, wid = tid >> 6;
  int l15 = lane & 15, lg = lane >> 4;
  int wr = (wid >> 1) * 32, wc = (wid & 1) * 32;
  int row0 = blockIdx.y * 64, col0 = blockIdx.x * 64;
  int sr = tid >> 2, sk = (tid & 3) * 16;
  const __hip_bfloat16* Ar = A + (size_t)(row0 + sr) * K + sk;
  const __hip_bfloat16* Br = Bt + (size_t)(col0 + sr) * K + sk;
  f32x4 zero4 = {0.f, 0.f, 0.f, 0.f};
  f32x4 acc[2][2];
#pragma unroll
  for (int i = 0; i < 2; i++)
#pragma unroll
    for (int j = 0; j < 2; j++) acc[i][j] = zero4;
  short8 ra0 = *(const short8*)(Ar);
  short8 ra1 = *(const short8*)(Ar + 8);
  short8 rb0 = *(const short8*)(Br);
  short8 rb1 = *(const short8*)(Br + 8);
  for (int k0 = 0; k0 < K; k0 += 64) {
    *(short8*)&As[sr][sk]     = ra0;
    *(short8*)&As[sr][sk + 8] = ra1;
    *(short8*)&Bs[sr][sk]     = rb0;
    *(short8*)&Bs[sr][sk + 8] = rb1;
    __syncthreads();
    if (k0 + 64 < K) {
      ra0 = *(const short8*)(Ar + k0 + 64);
      ra1 = *(const short8*)(Ar + k0 + 72);
      rb0 = *(const short8*)(Br + k0 + 64);
      rb1 = *(const short8*)(Br + k0 + 72);
    }
#pragma unroll
    for (int ks = 0; ks < 2; ks++) {
      short8 af[2], bf[2];
#pragma unroll
      for (int i = 0; i < 2; i++) af[i] = *(const short8*)&As[wr + i * 16 + l15][ks * 32 + lg * 8];
#pragma unroll
      for (int j = 0; j < 2; j++) bf[j] = *(const short8*)&Bs[wc + j * 16 + l15][ks * 32 + lg * 8];
#pragma unroll
      for (int i = 0; i < 2; i++)
#pragma unroll
        for (int j = 0; j < 2; j++)
          acc[i][j] = __builtin_amdgcn_mfma_f32_16x16x32_bf16(af[i], bf[j], acc[i][j], 0, 0, 0);
    }
    __syncthreads();
  }
#pragma unroll
  for (int i = 0; i < 2; i++)
#pragma unroll
    for (int r = 0; r < 4; r++) {
      int row = row0 + wr + i * 16 + lg * 4 + r;
#pragma unroll
      for (int j = 0; j < 2; j++) {
        int col = col0 + wc + j * 16 + l15;
        float v = acc[i][j][r];
        if (add) v += add[(size_t)row * N + col];
        C[(size_t)row * N + col] = v;
      }
    }
}

// ---------------- flash attention: block = (64 q-rows, head), 4 waves x 16 rows ----------------
__global__ __launch_bounds__(256) void attn_flash_k(
    const __hip_bfloat16* __restrict__ qb16, const __hip_bfloat16* __restrict__ kb16,
    const __hip_bfloat16* __restrict__ vbT, __hip_bfloat16* __restrict__ attnb) {
  __shared__ unsigned short Kl[32][72];     // 32 kv tokens x 64 dims
  __shared__ unsigned short Vt[64][40];     // 64 dims x 32 kv tokens
  __shared__ unsigned short Pl[4][16][40];  // per-wave P: 16 q x 32 kv
  int h = blockIdx.y, kvh = h >> 2;
  int q0 = blockIdx.x * 64;
  int tid = threadIdx.x, lane = tid & 63, wid = tid >> 6;
  int l15 = lane & 15, lg = lane >> 4;
  int qr0 = q0 + wid * 16;
  int q_lane = qr0 + l15;

  short8 bq[2];
  const __hip_bfloat16* qrow = qb16 + (size_t)(qr0 + l15) * Dm + h * 64;
  bq[0] = *(const short8*)(qrow + lg * 8);
  bq[1] = *(const short8*)(qrow + 32 + lg * 8);

  f32x4 zero4 = {0.f, 0.f, 0.f, 0.f};
  f32x4 oacc[4];
#pragma unroll
  for (int j = 0; j < 4; j++) oacc[j] = zero4;
  float m_run = -1e30f, lsum = 0.f;

  int nt = q0 / 32 + 2;
  int s_r = tid >> 3, s_off = (tid & 7) * 8;   // K staging
  int s_dd = tid >> 2, s_c = (tid & 3) * 8;    // V staging
  for (int t = 0; t < nt; t++) {
    int kv0 = t * 32;
    *(short8*)&Kl[s_r][s_off] = *(const short8*)(kb16 + (size_t)(kv0 + s_r) * 256 + kvh * 64 + s_off);
    *(short8*)&Vt[s_dd][s_c] = *(const short8*)(vbT + (size_t)(kvh * 64 + s_dd) * Sq + kv0 + s_c);
    __syncthreads();

    // S^T = K . Q^T  (col = q = l15, row = kv = lg*4+r)
    f32x4 sacc[2];
#pragma unroll
    for (int kvg = 0; kvg < 2; kvg++) {
      short8 ak0 = *(const short8*)&Kl[kvg * 16 + l15][lg * 8];
      short8 ak1 = *(const short8*)&Kl[kvg * 16 + l15][32 + lg * 8];
      f32x4 sa = __builtin_amdgcn_mfma_f32_16x16x32_bf16(ak0, bq[0], zero4, 0, 0, 0);
      sa = __builtin_amdgcn_mfma_f32_16x16x32_bf16(ak1, bq[1], sa, 0, 0, 0);
      sacc[kvg] = sa;
    }
    float s[8];
    float tmax = -1e30f;
#pragma unroll
    for (int kvg = 0; kvg < 2; kvg++)
#pragma unroll
      for (int r = 0; r < 4; r++) {
        int kv_abs = kv0 + kvg * 16 + lg * 4 + r;
        float v = sacc[kvg][r] * 0.125f;
        if (kv_abs > q_lane) v = -1e30f;
        s[kvg * 4 + r] = v;
        tmax = fmaxf(tmax, v);
      }
    tmax = fmaxf(tmax, __shfl_xor(tmax, 16));
    tmax = fmaxf(tmax, __shfl_xor(tmax, 32));
    float m_new = fmaxf(m_run, tmax);
    float corr = __expf(m_run - m_new);
    float psum = 0.f;
#pragma unroll
    for (int i = 0; i < 8; i++) { float p = __expf(s[i] - m_new); s[i] = p; psum += p; }
    psum += __shfl_xor(psum, 16);
    psum += __shfl_xor(psum, 32);
    lsum = lsum * corr + psum;
    m_run = m_new;
    float c4[4];
#pragma unroll
    for (int r = 0; r < 4; r++) c4[r] = __shfl(corr, lg * 4 + r);
#pragma unroll
    for (int j = 0; j < 4; j++)
#pragma unroll
      for (int r = 0; r < 4; r++) oacc[j][r] *= c4[r];
#pragma unroll
    for (int kvg = 0; kvg < 2; kvg++) {
      short4v p4;
#pragma unroll
      for (int r = 0; r < 4; r++) p4[r] = f2bf(s[kvg * 4 + r]);
      *(short4v*)&Pl[wid][l15][kvg * 16 + lg * 4] = p4;
    }
    short8 pa = *(const short8*)&Pl[wid][l15][lg * 8];
#pragma unroll
    for (int j = 0; j < 4; j++) {
      short8 vb = *(const short8*)&Vt[j * 16 + l15][lg * 8];
      oacc[j] = __builtin_amdgcn_mfma_f32_16x16x32_bf16(pa, vb, oacc[j], 0, 0, 0);
    }
    __syncthreads();
  }
  float inv = 1.f / lsum;
  float c4[4];
#pragma unroll
  for (int r = 0; r < 4; r++) c4[r] = __shfl(inv, lg * 4 + r);
#pragma unroll
  for (int j = 0; j < 4; j++)
#pragma unroll
    for (int r = 0; r < 4; r++) {
      int row = qr0 + lg * 4 + r;
      int col = h * 64 + j * 16 + l15;
      attnb[(size_t)row * Dm + col] = __float2bfloat16(oacc[j][r] * c4[r]);
    }
}

// ---------------- routing (fp32) ----------------
__global__ void route_k(const float* __restrict__ h2, const float* __restrict__ wg,
                        int* __restrict__ ti, float* __restrict__ tp) {
  int s = blockIdx.x, lane = threadIdx.x;
  float acc[8] = {0, 0, 0, 0, 0, 0, 0, 0};
  for (int dd = lane; dd < 1024; dd += 64) {
    float hv = h2[(size_t)s * 1024 + dd];
    const float* wr = wg + (size_t)dd * 8;
#pragma unroll
    for (int e = 0; e < 8; e++) acc[e] += hv * wr[e];
  }
#pragma unroll
  for (int off = 32; off > 0; off >>= 1) {
#pragma unroll
    for (int e = 0; e < 8; e++) acc[e] += __shfl_down(acc[e], off);
  }
  if (lane == 0) {
    float m = acc[0];
    for (int e = 1; e < 8; e++) m = fmaxf(m, acc[e]);
    float ex[8], sum = 0.f;
    for (int e = 0; e < 8; e++) { ex[e] = __expf(acc[e] - m); sum += ex[e]; }
    float inv = 1.f / sum;
    int i1 = 0;
    for (int e = 1; e < 8; e++) if (ex[e] > ex[i1]) i1 = e;
    int i2 = (i1 == 0) ? 1 : 0;
    for (int e = 0; e < 8; e++) if (e != i1 && ex[e] > ex[i2]) i2 = e;
    ti[2 * s] = i1; ti[2 * s + 1] = i2;
    tp[2 * s] = ex[i1] * inv; tp[2 * s + 1] = ex[i2] * inv;
  }
}

__global__ void scatter_k(const int* __restrict__ ti, int* __restrict__ cnt,
                          int* __restrict__ list) {
  int t = blockIdx.x * 256 + threadIdx.x;
  if (t < 2048) {
    int e = ti[t];
    int pos = atomicAdd(&cnt[e], 1);
    list[e * 1024 + pos] = t;  // t = s*2 + slot
  }
}

// ---------------- MoE up/gate (vectorized fp32 weight loads + 2-phase prefetch) ----------------
__global__ __launch_bounds__(256) void moe_upgate_k(
    const __hip_bfloat16* __restrict__ h2b, const float* __restrict__ up,
    const float* __restrict__ gate, const int* __restrict__ cnt,
    const int* __restrict__ list, __hip_bfloat16* __restrict__ hidden) {
  int e = blockIdx.z;
  int n = cnt[e];
  int ri0 = blockIdx.y * 64;
  if (ri0 >= n) return;
  __shared__ unsigned short As[64][72];
  __shared__ unsigned short Bu[64][72];
  __shared__ unsigned short Bg[64][72];
  int tid = threadIdx.x, lane = tid & 63, wid = tid >> 6;
  int l15 = lane & 15, lg = lane >> 4;
  int wr = (wid >> 1) * 32, wc = (wid & 1) * 32;
  int col0 = blockIdx.x * 64;
  int sr = tid >> 2, sk = (tid & 3) * 16;
  int gi = ri0 + sr;
  bool av = gi < n;
  int arow = av ? (list[e * 1024 + gi] >> 1) : 0;
  const float* upe = up + (size_t)e * 1024 * 1024 + (size_t)(col0 + sr) * 1024 + sk;
  const float* gte = gate + (size_t)e * 1024 * 1024 + (size_t)(col0 + sr) * 1024 + sk;
  const __hip_bfloat16* Ar = h2b + (size_t)arow * 1024 + sk;
  f32x4 zero4 = {0.f, 0.f, 0.f, 0.f};
  f32x4 aU[2][2], aG[2][2];
#pragma unroll
  for (int i = 0; i < 2; i++)
#pragma unroll
    for (int j = 0; j < 2; j++) { aU[i][j] = zero4; aG[i][j] = zero4; }

  short8 ra0 = {}, ra1 = {};
  f32x4 ru[4], rg[4];
  // prologue load k0=0
  if (av) { ra0 = *(const short8*)(Ar); ra1 = *(const short8*)(Ar + 8); }
  {
    const f32x4* pu4 = (const f32x4*)(upe);
    const f32x4* pg4 = (const f32x4*)(gte);
#pragma unroll
    for (int q = 0; q < 4; q++) { ru[q] = pu4[q]; rg[q] = pg4[q]; }
  }
  for (int k0 = 0; k0 < 1024; k0 += 64) {
    // write staged regs to LDS (fp32 -> bf16 for weights)
    *(short8*)&As[sr][sk]     = ra0;
    *(short8*)&As[sr][sk + 8] = ra1;
    short8 ub0, ub1, gb0, gb1;
#pragma unroll
    for (int q = 0; q < 8; q++) {
      ub0[q] = f2bf(ru[q >> 2][q & 3]);     gb0[q] = f2bf(rg[q >> 2][q & 3]);
      ub1[q] = f2bf(ru[2 + (q >> 2)][q & 3]); gb1[q] = f2bf(rg[2 + (q >> 2)][q & 3]);
    }
    *(short8*)&Bu[sr][sk]     = ub0;
    *(short8*)&Bu[sr][sk + 8] = ub1;
    *(short8*)&Bg[sr][sk]     = gb0;
    *(short8*)&Bg[sr][sk + 8] = gb1;
    __syncthreads();
    // prefetch next chunk (flies under MFMA)
    if (k0 + 64 < 1024) {
      if (av) { ra0 = *(const short8*)(Ar + k0 + 64); ra1 = *(const short8*)(Ar + k0 + 72); }
      const f32x4* pu4 = (const f32x4*)(upe + k0 + 64);
      const f32x4* pg4 = (const f32x4*)(gte + k0 + 64);
#pragma unroll
      for (int q = 0; q < 4; q++) { ru[q] = pu4[q]; rg[q] = pg4[q]; }
    }
#pragma unroll
    for (int ks = 0; ks < 2; ks++) {
      short8 af[2], bu[2], bg[2];
#pragma unroll
      for (int i = 0; i < 2; i++) af[i] = *(const short8*)&As[wr + i * 16 + l15][ks * 32 + lg * 8];
#pragma unroll
      for (int j = 0; j < 2; j++) {
        bu[j] = *(const short8*)&Bu[wc + j * 16 + l15][ks * 32 + lg * 8];
        bg[j] = *(const short8*)&Bg[wc + j * 16 + l15][ks * 32 + lg * 8];
      }
#pragma unroll
      for (int i = 0; i < 2; i++)
#pragma unroll
        for (int j = 0; j < 2; j++) {
          aU[i][j] = __builtin_amdgcn_mfma_f32_16x16x32_bf16(af[i], bu[j], aU[i][j], 0, 0, 0);
          aG[i][j] = __builtin_amdgcn_mfma_f32_16x16x32_bf16(af[i], bg[j], aG[i][j], 0, 0, 0);
        }
    }
    __syncthreads();
  }
#pragma unroll
  for (int i = 0; i < 2; i++)
#pragma unroll
    for (int r = 0; r < 4; r++) {
      int gi2 = ri0 + wr + i * 16 + lg * 4 + r;
      if (gi2 < n) {
        int s2 = list[e * 1024 + gi2];
#pragma unroll
        for (int j = 0; j < 2; j++) {
          int col = col0 + wc + j * 16 + l15;
          float g = aG[i][j][r], u = aU[i][j][r];
          float sil = g / (1.f + __expf(-g));
          hidden[(size_t)s2 * 1024 + col] = __float2bfloat16(sil * u);
        }
      }
    }
}

// ---------------- MoE down (vectorized + prefetch) ----------------
__global__ __launch_bounds__(256) void moe_down_k(
    const __hip_bfloat16* __restrict__ hidden, const float* __restrict__ dp,
    const int* __restrict__ cnt, const int* __restrict__ list,
    const float* __restrict__ tp, float* __restrict__ dbuf) {
  int e = blockIdx.z;
  int n = cnt[e];
  int ri0 = blockIdx.y * 64;
  if (ri0 >= n) return;
  __shared__ unsigned short As[64][72];
  __shared__ unsigned short Bs[64][72];
  int tid = threadIdx.x, lane = tid & 63, wid = tid >> 6;
  int l15 = lane & 15, lg = lane >> 4;
  int wr = (wid >> 1) * 32, wc = (wid & 1) * 32;
  int col0 = blockIdx.x * 64;
  int sr = tid >> 2, sk = (tid & 3) * 16;
  int gi = ri0 + sr;
  bool av = gi < n;
  int arow = av ? list[e * 1024 + gi] : 0;
  const float* dpe = dp + (size_t)e * 1024 * 1024 + (size_t)(col0 + sr) * 1024 + sk;
  const __hip_bfloat16* Ar = hidden + (size_t)arow * 1024 + sk;
  f32x4 zero4 = {0.f, 0.f, 0.f, 0.f};
  f32x4 acc[2][2];
#pragma unroll
  for (int i = 0; i < 2; i++)
#pragma unroll
    for (int j = 0; j < 2; j++) acc[i][j] = zero4;

  short8 ra0 = {}, ra1 = {};
  f32x4 rb[4];
  if (av) { ra0 = *(const short8*)(Ar); ra1 = *(const short8*)(Ar + 8); }
  {
    const f32x4* pb4 = (const f32x4*)(dpe);
#pragma unroll
    for (int q = 0; q < 4; q++) rb[q] = pb4[q];
  }
  for (int k0 = 0; k0 < 1024; k0 += 64) {
    *(short8*)&As[sr][sk]     = ra0;
    *(short8*)&As[sr][sk + 8] = ra1;
    short8 bb0, bb1;
#pragma unroll
    for (int q = 0; q < 8; q++) {
      bb0[q] = f2bf(rb[q >> 2][q & 3]);
      bb1[q] = f2bf(rb[2 + (q >> 2)][q & 3]);
    }
    *(short8*)&Bs[sr][sk]     = bb0;
    *(short8*)&Bs[sr][sk + 8] = bb1;
    __syncthreads();
    if (k0 + 64 < 1024) {
      if (av) { ra0 = *(const short8*)(Ar + k0 + 64); ra1 = *(const short8*)(Ar + k0 + 72); }
      const f32x4* pb4 = (const f32x4*)(dpe + k0 + 64);
#pragma unroll
      for (int q = 0; q < 4; q++) rb[q] = pb4[q];
    }
#pragma unroll
    for (int ks = 0; ks < 2; ks++) {
      short8 af[2], bf[2];
#pragma unroll
      for (int i = 0; i < 2; i++) af[i] = *(const short8*)&As[wr + i * 16 + l15][ks * 32 + lg * 8];
#pragma unroll
      for (int j = 0; j < 2; j++) bf[j] = *(const short8*)&Bs[wc + j * 16 + l15][ks * 32 + lg * 8];
#pragma unroll
      for (int i = 0; i < 2; i++)
#pragma unroll
        for (int j = 0; j < 2; j++)
          acc[i][j] = __builtin_amdgcn_mfma_f32_16x16x32_bf16(af[i], bf[j], acc[i][j], 0, 0, 0);
    }
    __syncthreads();
  }
#pragma unroll
  for (int i = 0; i < 2; i++)
#pragma unroll
    for (int r = 0; r < 4; r++) {
      int gi2 = ri0 + wr + i * 16 + lg * 4 + r;
      if (gi2 < n) {
        int s2 = list[e * 1024 + gi2];
        float p = tp[s2];
#pragma unroll
        for (int j = 0; j < 2; j++) {
          int col = col0 + wc + j * 16 + l15;
          dbuf[(size_t)s2 * 1024 + col] = p * acc[i][j][r];
        }
      }
    }
}

__global__ void final_add_k(const float* __restrict__ x2, const float* __restrict__ dbuf,
                            float* __restrict__ out) {
  int s = blockIdx.x, t = threadIdx.x;
  f32x4 a = *(const f32x4*)(x2 + (size_t)s * 1024 + t * 4);
  f32x4 b = *(const f32x4*)(dbuf + (size_t)(2 * s) * 1024 + t * 4);
  f32x4 c = *(const f32x4*)(dbuf + (size_t)(2 * s + 1) * 1024 + t * 4);
  f32x4 o;
#pragma unroll
  for (int r = 0; r < 4; r++) o[r] = a[r] + b[r] + c[r];
  *(f32x4*)(out + (size_t)s * 1024 + t * 4) = o;
}

extern "C" void kernel_launch(void* const* d_in, const int* in_sizes, int n_in,
                              void* d_out, int out_size, void* d_ws, size_t ws_size,
                              hipStream_t stream) {
  const float* x    = (const float*)d_in[0];
  const float* cosb = (const float*)d_in[1];
  const float* sinb = (const float*)d_in[2];
  const float* w_in = (const float*)d_in[5];
  const float* wq   = (const float*)d_in[6];
  const float* wk   = (const float*)d_in[7];
  const float* wv   = (const float*)d_in[8];
  const float* wo   = (const float*)d_in[9];
  const float* w_qn = (const float*)d_in[10];
  const float* w_kn = (const float*)d_in[11];
  const float* w_pn = (const float*)d_in[12];
  const float* wg   = (const float*)d_in[13];
  const float* up   = (const float*)d_in[14];
  const float* gate = (const float*)d_in[15];
  const float* dp   = (const float*)d_in[16];
  float* out = (float*)d_out;

  char* w = (char*)d_ws;
  const size_t MB = 1024 * 1024;
  __hip_bfloat16* hb    = (__hip_bfloat16*)w; w += 2 * MB;
  __hip_bfloat16* woT   = (__hip_bfloat16*)w; w += 2 * MB;
  // ---- dbuf alias region: qb(4) + kbf(1) + vbf(1) + wqT(2) = 8MB ----
  float* qb             = (float*)w;          w += 4 * MB;
  float* kbf            = (float*)w;          w += 1 * MB;
  float* vbf            = (float*)w;          w += 1 * MB;
  __hip_bfloat16* wqT   = (__hip_bfloat16*)w; w += 2 * MB;
  // -------------------------------------------------------------------
  __hip_bfloat16* wkT   = (__hip_bfloat16*)w; w += MB / 2;
  __hip_bfloat16* wvT   = (__hip_bfloat16*)w; w += MB / 2;
  __hip_bfloat16* qb16  = (__hip_bfloat16*)w; w += 2 * MB;
  __hip_bfloat16* kb16  = (__hip_bfloat16*)w; w += MB / 2;
  __hip_bfloat16* vbT   = (__hip_bfloat16*)w; w += MB / 2;
  __hip_bfloat16* attnb = (__hip_bfloat16*)w; w += 2 * MB;
  float* x2             = (float*)w;          w += 4 * MB;
  float* h2f            = (float*)w;          w += 4 * MB;
  __hip_bfloat16* h2b   = (__hip_bfloat16*)w; w += 2 * MB;
  __hip_bfloat16* hidden= (__hip_bfloat16*)w; w += 4 * MB;
  float* tp             = (float*)w;          w += 2048 * 4;
  int* ti               = (int*)w;            w += 2048 * 4;
  int* cnt              = (int*)w;            w += 64 * 4;
  int* list             = (int*)w;            w += 8192 * 4;
  float* dbuf = qb;  // 8MB alias (qb/kbf/vbf/wqT all dead by MoE-down time)

  hipMemsetAsync(cnt, 0, 8 * sizeof(int), stream);

  transpose_cast_k<<<dim3(32, 32), dim3(32, 8), 0, stream>>>(wq, wqT, 1024, 1024);
  transpose_cast_k<<<dim3(8, 32),  dim3(32, 8), 0, stream>>>(wk, wkT, 1024, 256);
  transpose_cast_k<<<dim3(8, 32),  dim3(32, 8), 0, stream>>>(wv, wvT, 1024, 256);
  transpose_cast_k<<<dim3(32, 32), dim3(32, 8), 0, stream>>>(wo, woT, 1024, 1024);

  rmsnorm_b16_k<<<Sq, 256, 0, stream>>>(x, w_in, hb);
  gemm_nt_k<<<dim3(16, 16), 256, 0, stream>>>(hb, wqT, nullptr, qb, 1024, 1024, 1024);
  gemm_nt_k<<<dim3(4, 16),  256, 0, stream>>>(hb, wkT, nullptr, kbf, 1024, 256, 1024);
  gemm_nt_k<<<dim3(4, 16),  256, 0, stream>>>(hb, wvT, nullptr, vbf, 1024, 256, 1024);

  normrope_b16_k<<<Sq, 256, 0, stream>>>(qb, w_qn, cosb, sinb, qb16, 1024);
  normrope_b16_k<<<Sq, 256, 0, stream>>>(kbf, w_kn, cosb, sinb, kb16, 256);
  transpose_cast_k<<<dim3(8, 32), dim3(32, 8), 0, stream>>>(vbf, vbT, 1024, 256);

  attn_flash_k<<<dim3(16, 16), 256, 0, stream>>>(qb16, kb16, vbT, attnb);
  gemm_nt_k<<<dim3(16, 16), 256, 0, stream>>>(attnb, woT, x, x2, 1024, 1024, 1024);

  rmsnorm_dual_k<<<Sq, 256, 0, stream>>>(x2, w_pn, h2f, h2b);
  route_k<<<Sq, 64, 0, stream>>>(h2f, wg, ti, tp);
  scatter_k<<<8, 256, 0, stream>>>(ti, cnt, list);
  moe_upgate_k<<<dim3(16, 16, 8), 256, 0, stream>>>(h2b, up, gate, cnt, list, hidden);
  moe_down_k<<<dim3(16, 16, 8), 256, 0, stream>>>(hidden, dp, cnt, list, tp, dbuf);
  final_add_k<<<Sq, 256, 0, stream>>>(x2, dbuf, out);
}

// Round 6
// 341.403 us; speedup vs baseline: 4.4348x; 1.0645x over previous
//
#include <hip/hip_runtime.h>
#include <hip/hip_bf16.h>

#define Sq 1024
#define Dm 1024
#define Hh 16
#define EPS 1e-5f

typedef __attribute__((ext_vector_type(8))) short short8;
typedef __attribute__((ext_vector_type(4))) short short4v;
typedef __attribute__((ext_vector_type(4))) float f32x4;

static __device__ __forceinline__ short f2bf(float f) {
  __hip_bfloat16 h = __float2bfloat16(f);
  return *reinterpret_cast<short*>(&h);
}

static __device__ __forceinline__ short8 cvt2(f32x4 x, f32x4 y) {
  short8 r;
  r[0] = f2bf(x[0]); r[1] = f2bf(x[1]); r[2] = f2bf(x[2]); r[3] = f2bf(x[3]);
  r[4] = f2bf(y[0]); r[5] = f2bf(y[1]); r[6] = f2bf(y[2]); r[7] = f2bf(y[3]);
  return r;
}

// ---------------- transpose + cast: in fp32 [R][C] -> out bf16 [C][R] ----------------
__global__ void transpose_cast_k(const float* __restrict__ in, __hip_bfloat16* __restrict__ outT,
                                 int R, int Cc) {
  __shared__ float t[32][33];
  int c0 = blockIdx.x * 32, r0 = blockIdx.y * 32;
  int tx = threadIdx.x, ty = threadIdx.y;
#pragma unroll
  for (int i = 0; i < 32; i += 8)
    t[ty + i][tx] = in[(size_t)(r0 + ty + i) * Cc + c0 + tx];
  __syncthreads();
#pragma unroll
  for (int i = 0; i < 32; i += 8)
    outT[(size_t)(c0 + ty + i) * R + r0 + tx] = __float2bfloat16(t[tx][ty + i]);
}

// ---------------- rmsnorm -> bf16 ----------------
__global__ void rmsnorm_b16_k(const float* __restrict__ in, const float* __restrict__ w,
                              __hip_bfloat16* __restrict__ outb) {
  int s = blockIdx.x, t = threadIdx.x;
  __shared__ float wsum[4];
  f32x4 v = *(const f32x4*)(in + (size_t)s * Dm + t * 4);
  float local = v[0] * v[0] + v[1] * v[1] + v[2] * v[2] + v[3] * v[3];
#pragma unroll
  for (int off = 32; off > 0; off >>= 1) local += __shfl_xor(local, off);
  if ((t & 63) == 0) wsum[t >> 6] = local;
  __syncthreads();
  float scale = rsqrtf((wsum[0] + wsum[1] + wsum[2] + wsum[3]) * (1.f / Dm) + EPS);
  f32x4 wv = *(const f32x4*)(w + t * 4);
  short4v o;
#pragma unroll
  for (int r = 0; r < 4; r++) o[r] = f2bf(v[r] * scale * wv[r]);
  *(short4v*)((unsigned short*)outb + (size_t)s * Dm + t * 4) = o;
}

// ---------------- rmsnorm -> fp32 + bf16 ----------------
__global__ void rmsnorm_dual_k(const float* __restrict__ in, const float* __restrict__ w,
                               float* __restrict__ outf, __hip_bfloat16* __restrict__ outb) {
  int s = blockIdx.x, t = threadIdx.x;
  __shared__ float wsum[4];
  f32x4 v = *(const f32x4*)(in + (size_t)s * Dm + t * 4);
  float local = v[0] * v[0] + v[1] * v[1] + v[2] * v[2] + v[3] * v[3];
#pragma unroll
  for (int off = 32; off > 0; off >>= 1) local += __shfl_xor(local, off);
  if ((t & 63) == 0) wsum[t >> 6] = local;
  __syncthreads();
  float scale = rsqrtf((wsum[0] + wsum[1] + wsum[2] + wsum[3]) * (1.f / Dm) + EPS);
  f32x4 wv = *(const f32x4*)(w + t * 4);
  f32x4 of;
  short4v o;
#pragma unroll
  for (int r = 0; r < 4; r++) { of[r] = v[r] * scale * wv[r]; o[r] = f2bf(of[r]); }
  *(f32x4*)(outf + (size_t)s * Dm + t * 4) = of;
  *(short4v*)((unsigned short*)outb + (size_t)s * Dm + t * 4) = o;
}

// ---------------- fused rmsnorm + RoPE -> bf16 ----------------
__global__ void normrope_b16_k(const float* __restrict__ in, const float* __restrict__ w,
                               const float* __restrict__ cosb, const float* __restrict__ sinb,
                               __hip_bfloat16* __restrict__ outb, int W) {
  int s = blockIdx.x, t = threadIdx.x;
  __shared__ float rowb[1024];
  __shared__ float wsum[4];
  const float* row = in + (size_t)s * W;
  bool act = t * 4 < W;
  f32x4 v = {};
  float local = 0.f;
  if (act) {
    v = *(const f32x4*)(row + t * 4);
    *(f32x4*)&rowb[t * 4] = v;
    local = v[0] * v[0] + v[1] * v[1] + v[2] * v[2] + v[3] * v[3];
  }
#pragma unroll
  for (int off = 32; off > 0; off >>= 1) local += __shfl_xor(local, off);
  if ((t & 63) == 0) wsum[t >> 6] = local;
  __syncthreads();
  if (!act) return;
  float scale = rsqrtf((wsum[0] + wsum[1] + wsum[2] + wsum[3]) / W + EPS);
  int i0 = t * 4, hd = i0 & 63;
  int pair0 = (hd < 32) ? i0 + 32 : i0 - 32;
  f32x4 pv = *(const f32x4*)&rowb[pair0];
  f32x4 wv = *(const f32x4*)(w + i0);
  f32x4 wp = *(const f32x4*)(w + pair0);
  float sgn = (hd < 32) ? -1.f : 1.f;
  short4v o;
#pragma unroll
  for (int r = 0; r < 4; r++) {
    float c = cosb[s * 64 + hd + r], si = sinb[s * 64 + hd + r];
    o[r] = f2bf(v[r] * scale * wv[r] * c + sgn * pv[r] * scale * wp[r] * si);
  }
  *(short4v*)((unsigned short*)outb + (size_t)s * W + i0) = o;
}

// ---------------- dense NT GEMM, 2-deep reg prefetch ----------------
struct StageG { short8 a0, a1, b0, b1; };

__global__ __launch_bounds__(256) void gemm_nt_k(
    const __hip_bfloat16* __restrict__ A, const __hip_bfloat16* __restrict__ Bt,
    const float* __restrict__ add, float* __restrict__ C, int M, int N, int K) {
  __shared__ unsigned short As[64][72];
  __shared__ unsigned short Bs[64][72];
  int tid = threadIdx.x, lane = tid & 63, wid = tid >> 6;
  int l15 = lane & 15, lg = lane >> 4;
  int wr = (wid >> 1) * 32, wc = (wid & 1) * 32;
  int row0 = blockIdx.y * 64, col0 = blockIdx.x * 64;
  int sr = tid >> 2, sk = (tid & 3) * 16;
  const __hip_bfloat16* Ar = A + (size_t)(row0 + sr) * K + sk;
  const __hip_bfloat16* Br = Bt + (size_t)(col0 + sr) * K + sk;
  f32x4 zero4 = {0.f, 0.f, 0.f, 0.f};
  f32x4 acc[2][2];
#pragma unroll
  for (int i = 0; i < 2; i++)
#pragma unroll
    for (int j = 0; j < 2; j++) acc[i][j] = zero4;

  auto g_load = [&](StageG& s, int k) {
    s.a0 = *(const short8*)(Ar + k); s.a1 = *(const short8*)(Ar + k + 8);
    s.b0 = *(const short8*)(Br + k); s.b1 = *(const short8*)(Br + k + 8);
  };
  auto g_write = [&](const StageG& s) {
    *(short8*)&As[sr][sk]     = s.a0;
    *(short8*)&As[sr][sk + 8] = s.a1;
    *(short8*)&Bs[sr][sk]     = s.b0;
    *(short8*)&Bs[sr][sk + 8] = s.b1;
  };
  auto do_mfma = [&]() {
#pragma unroll
    for (int ks = 0; ks < 2; ks++) {
      short8 af[2], bf[2];
#pragma unroll
      for (int i = 0; i < 2; i++) af[i] = *(const short8*)&As[wr + i * 16 + l15][ks * 32 + lg * 8];
#pragma unroll
      for (int j = 0; j < 2; j++) bf[j] = *(const short8*)&Bs[wc + j * 16 + l15][ks * 32 + lg * 8];
#pragma unroll
      for (int i = 0; i < 2; i++)
#pragma unroll
        for (int j = 0; j < 2; j++)
          acc[i][j] = __builtin_amdgcn_mfma_f32_16x16x32_bf16(af[i], bf[j], acc[i][j], 0, 0, 0);
    }
  };

  StageG s0 = {}, s1 = {};
  g_load(s0, 0);
  g_load(s1, 64);
  for (int k0 = 0; k0 < K; k0 += 128) {   // K must be a multiple of 128 (K=1024 here)
    g_write(s0);
    __syncthreads();
    if (k0 + 128 < K) g_load(s0, k0 + 128);
    do_mfma();
    __syncthreads();
    g_write(s1);
    __syncthreads();
    if (k0 + 192 < K) g_load(s1, k0 + 192);
    do_mfma();
    __syncthreads();
  }
#pragma unroll
  for (int i = 0; i < 2; i++)
#pragma unroll
    for (int r = 0; r < 4; r++) {
      int row = row0 + wr + i * 16 + lg * 4 + r;
#pragma unroll
      for (int j = 0; j < 2; j++) {
        int col = col0 + wc + j * 16 + l15;
        float v = acc[i][j][r];
        if (add) v += add[(size_t)row * N + col];
        C[(size_t)row * N + col] = v;
      }
    }
}

// ---------------- flash attention: block = (64 q-rows, head), 4 waves x 16 rows ----------------
__global__ __launch_bounds__(256) void attn_flash_k(
    const __hip_bfloat16* __restrict__ qb16, const __hip_bfloat16* __restrict__ kb16,
    const __hip_bfloat16* __restrict__ vbT, __hip_bfloat16* __restrict__ attnb) {
  __shared__ unsigned short Kl[32][72];
  __shared__ unsigned short Vt[64][40];
  __shared__ unsigned short Pl[4][16][40];
  int h = blockIdx.y, kvh = h >> 2;
  int q0 = blockIdx.x * 64;
  int tid = threadIdx.x, lane = tid & 63, wid = tid >> 6;
  int l15 = lane & 15, lg = lane >> 4;
  int qr0 = q0 + wid * 16;
  int q_lane = qr0 + l15;

  short8 bq[2];
  const __hip_bfloat16* qrow = qb16 + (size_t)(qr0 + l15) * Dm + h * 64;
  bq[0] = *(const short8*)(qrow + lg * 8);
  bq[1] = *(const short8*)(qrow + 32 + lg * 8);

  f32x4 zero4 = {0.f, 0.f, 0.f, 0.f};
  f32x4 oacc[4];
#pragma unroll
  for (int j = 0; j < 4; j++) oacc[j] = zero4;
  float m_run = -1e30f, lsum = 0.f;

  int nt = q0 / 32 + 2;
  int s_r = tid >> 3, s_off = (tid & 7) * 8;
  int s_dd = tid >> 2, s_c = (tid & 3) * 8;
  for (int t = 0; t < nt; t++) {
    int kv0 = t * 32;
    *(short8*)&Kl[s_r][s_off] = *(const short8*)(kb16 + (size_t)(kv0 + s_r) * 256 + kvh * 64 + s_off);
    *(short8*)&Vt[s_dd][s_c] = *(const short8*)(vbT + (size_t)(kvh * 64 + s_dd) * Sq + kv0 + s_c);
    __syncthreads();

    f32x4 sacc[2];
#pragma unroll
    for (int kvg = 0; kvg < 2; kvg++) {
      short8 ak0 = *(const short8*)&Kl[kvg * 16 + l15][lg * 8];
      short8 ak1 = *(const short8*)&Kl[kvg * 16 + l15][32 + lg * 8];
      f32x4 sa = __builtin_amdgcn_mfma_f32_16x16x32_bf16(ak0, bq[0], zero4, 0, 0, 0);
      sa = __builtin_amdgcn_mfma_f32_16x16x32_bf16(ak1, bq[1], sa, 0, 0, 0);
      sacc[kvg] = sa;
    }
    float s[8];
    float tmax = -1e30f;
#pragma unroll
    for (int kvg = 0; kvg < 2; kvg++)
#pragma unroll
      for (int r = 0; r < 4; r++) {
        int kv_abs = kv0 + kvg * 16 + lg * 4 + r;
        float v = sacc[kvg][r] * 0.125f;
        if (kv_abs > q_lane) v = -1e30f;
        s[kvg * 4 + r] = v;
        tmax = fmaxf(tmax, v);
      }
    tmax = fmaxf(tmax, __shfl_xor(tmax, 16));
    tmax = fmaxf(tmax, __shfl_xor(tmax, 32));
    float m_new = fmaxf(m_run, tmax);
    float corr = __expf(m_run - m_new);
    float psum = 0.f;
#pragma unroll
    for (int i = 0; i < 8; i++) { float p = __expf(s[i] - m_new); s[i] = p; psum += p; }
    psum += __shfl_xor(psum, 16);
    psum += __shfl_xor(psum, 32);
    lsum = lsum * corr + psum;
    m_run = m_new;
    float c4[4];
#pragma unroll
    for (int r = 0; r < 4; r++) c4[r] = __shfl(corr, lg * 4 + r);
#pragma unroll
    for (int j = 0; j < 4; j++)
#pragma unroll
      for (int r = 0; r < 4; r++) oacc[j][r] *= c4[r];
#pragma unroll
    for (int kvg = 0; kvg < 2; kvg++) {
      short4v p4;
#pragma unroll
      for (int r = 0; r < 4; r++) p4[r] = f2bf(s[kvg * 4 + r]);
      *(short4v*)&Pl[wid][l15][kvg * 16 + lg * 4] = p4;
    }
    short8 pa = *(const short8*)&Pl[wid][l15][lg * 8];
#pragma unroll
    for (int j = 0; j < 4; j++) {
      short8 vb = *(const short8*)&Vt[j * 16 + l15][lg * 8];
      oacc[j] = __builtin_amdgcn_mfma_f32_16x16x32_bf16(pa, vb, oacc[j], 0, 0, 0);
    }
    __syncthreads();
  }
  float inv = 1.f / lsum;
  float c4[4];
#pragma unroll
  for (int r = 0; r < 4; r++) c4[r] = __shfl(inv, lg * 4 + r);
#pragma unroll
  for (int j = 0; j < 4; j++)
#pragma unroll
    for (int r = 0; r < 4; r++) {
      int row = qr0 + lg * 4 + r;
      int col = h * 64 + j * 16 + l15;
      attnb[(size_t)row * Dm + col] = __float2bfloat16(oacc[j][r] * c4[r]);
    }
}

// ---------------- routing (fp32) ----------------
__global__ void route_k(const float* __restrict__ h2, const float* __restrict__ wg,
                        int* __restrict__ ti, float* __restrict__ tp) {
  int s = blockIdx.x, lane = threadIdx.x;
  float acc[8] = {0, 0, 0, 0, 0, 0, 0, 0};
  for (int dd = lane; dd < 1024; dd += 64) {
    float hv = h2[(size_t)s * 1024 + dd];
    const float* wr = wg + (size_t)dd * 8;
#pragma unroll
    for (int e = 0; e < 8; e++) acc[e] += hv * wr[e];
  }
#pragma unroll
  for (int off = 32; off > 0; off >>= 1) {
#pragma unroll
    for (int e = 0; e < 8; e++) acc[e] += __shfl_down(acc[e], off);
  }
  if (lane == 0) {
    float m = acc[0];
    for (int e = 1; e < 8; e++) m = fmaxf(m, acc[e]);
    float ex[8], sum = 0.f;
    for (int e = 0; e < 8; e++) { ex[e] = __expf(acc[e] - m); sum += ex[e]; }
    float inv = 1.f / sum;
    int i1 = 0;
    for (int e = 1; e < 8; e++) if (ex[e] > ex[i1]) i1 = e;
    int i2 = (i1 == 0) ? 1 : 0;
    for (int e = 0; e < 8; e++) if (e != i1 && ex[e] > ex[i2]) i2 = e;
    ti[2 * s] = i1; ti[2 * s + 1] = i2;
    tp[2 * s] = ex[i1] * inv; tp[2 * s + 1] = ex[i2] * inv;
  }
}

__global__ void scatter_k(const int* __restrict__ ti, int* __restrict__ cnt,
                          int* __restrict__ list) {
  int t = blockIdx.x * 256 + threadIdx.x;
  if (t < 2048) {
    int e = ti[t];
    int pos = atomicAdd(&cnt[e], 1);
    list[e * 1024 + pos] = t;  // t = s*2 + slot
  }
}

// ---------------- MoE up/gate, 2-deep prefetch ----------------
struct StageUG { short8 a0, a1; f32x4 u0, u1, u2, u3, g0, g1, g2, g3; };

__global__ __launch_bounds__(256) void moe_upgate_k(
    const __hip_bfloat16* __restrict__ h2b, const float* __restrict__ up,
    const float* __restrict__ gate, const int* __restrict__ cnt,
    const int* __restrict__ list, __hip_bfloat16* __restrict__ hidden) {
  int e = blockIdx.z;
  int n = cnt[e];
  int ri0 = blockIdx.y * 64;
  if (ri0 >= n) return;
  __shared__ unsigned short As[64][72];
  __shared__ unsigned short Bu[64][72];
  __shared__ unsigned short Bg[64][72];
  int tid = threadIdx.x, lane = tid & 63, wid = tid >> 6;
  int l15 = lane & 15, lg = lane >> 4;
  int wr = (wid >> 1) * 32, wc = (wid & 1) * 32;
  int col0 = blockIdx.x * 64;
  int sr = tid >> 2, sk = (tid & 3) * 16;
  int gi = ri0 + sr;
  bool av = gi < n;
  int arow = av ? (list[e * 1024 + gi] >> 1) : 0;
  const float* upe = up + (size_t)e * 1024 * 1024 + (size_t)(col0 + sr) * 1024 + sk;
  const float* gte = gate + (size_t)e * 1024 * 1024 + (size_t)(col0 + sr) * 1024 + sk;
  const __hip_bfloat16* Ar = h2b + (size_t)arow * 1024 + sk;
  f32x4 zero4 = {0.f, 0.f, 0.f, 0.f};
  f32x4 aU[2][2], aG[2][2];
#pragma unroll
  for (int i = 0; i < 2; i++)
#pragma unroll
    for (int j = 0; j < 2; j++) { aU[i][j] = zero4; aG[i][j] = zero4; }

  auto ug_load = [&](StageUG& s, int k) {
    if (av) { s.a0 = *(const short8*)(Ar + k); s.a1 = *(const short8*)(Ar + k + 8); }
    const f32x4* pu = (const f32x4*)(upe + k);
    const f32x4* pg = (const f32x4*)(gte + k);
    s.u0 = pu[0]; s.u1 = pu[1]; s.u2 = pu[2]; s.u3 = pu[3];
    s.g0 = pg[0]; s.g1 = pg[1]; s.g2 = pg[2]; s.g3 = pg[3];
  };
  auto ug_write = [&](const StageUG& s) {
    *(short8*)&As[sr][sk]     = s.a0;
    *(short8*)&As[sr][sk + 8] = s.a1;
    *(short8*)&Bu[sr][sk]     = cvt2(s.u0, s.u1);
    *(short8*)&Bu[sr][sk + 8] = cvt2(s.u2, s.u3);
    *(short8*)&Bg[sr][sk]     = cvt2(s.g0, s.g1);
    *(short8*)&Bg[sr][sk + 8] = cvt2(s.g2, s.g3);
  };
  auto do_mfma = [&]() {
#pragma unroll
    for (int ks = 0; ks < 2; ks++) {
      short8 af[2], bu[2], bg[2];
#pragma unroll
      for (int i = 0; i < 2; i++) af[i] = *(const short8*)&As[wr + i * 16 + l15][ks * 32 + lg * 8];
#pragma unroll
      for (int j = 0; j < 2; j++) {
        bu[j] = *(const short8*)&Bu[wc + j * 16 + l15][ks * 32 + lg * 8];
        bg[j] = *(const short8*)&Bg[wc + j * 16 + l15][ks * 32 + lg * 8];
      }
#pragma unroll
      for (int i = 0; i < 2; i++)
#pragma unroll
        for (int j = 0; j < 2; j++) {
          aU[i][j] = __builtin_amdgcn_mfma_f32_16x16x32_bf16(af[i], bu[j], aU[i][j], 0, 0, 0);
          aG[i][j] = __builtin_amdgcn_mfma_f32_16x16x32_bf16(af[i], bg[j], aG[i][j], 0, 0, 0);
        }
    }
  };

  StageUG s0 = {}, s1 = {};
  ug_load(s0, 0);
  ug_load(s1, 64);
  for (int k0 = 0; k0 < 1024; k0 += 128) {
    ug_write(s0);
    __syncthreads();
    if (k0 + 128 < 1024) ug_load(s0, k0 + 128);
    do_mfma();
    __syncthreads();
    ug_write(s1);
    __syncthreads();
    if (k0 + 192 < 1024) ug_load(s1, k0 + 192);
    do_mfma();
    __syncthreads();
  }
#pragma unroll
  for (int i = 0; i < 2; i++)
#pragma unroll
    for (int r = 0; r < 4; r++) {
      int gi2 = ri0 + wr + i * 16 + lg * 4 + r;
      if (gi2 < n) {
        int s2 = list[e * 1024 + gi2];
#pragma unroll
        for (int j = 0; j < 2; j++) {
          int col = col0 + wc + j * 16 + l15;
          float g = aG[i][j][r], u = aU[i][j][r];
          float sil = g / (1.f + __expf(-g));
          hidden[(size_t)s2 * 1024 + col] = __float2bfloat16(sil * u);
        }
      }
    }
}

// ---------------- MoE down, 2-deep prefetch ----------------
struct StageD { short8 a0, a1; f32x4 b0, b1, b2, b3; };

__global__ __launch_bounds__(256) void moe_down_k(
    const __hip_bfloat16* __restrict__ hidden, const float* __restrict__ dp,
    const int* __restrict__ cnt, const int* __restrict__ list,
    const float* __restrict__ tp, float* __restrict__ dbuf) {
  int e = blockIdx.z;
  int n = cnt[e];
  int ri0 = blockIdx.y * 64;
  if (ri0 >= n) return;
  __shared__ unsigned short As[64][72];
  __shared__ unsigned short Bs[64][72];
  int tid = threadIdx.x, lane = tid & 63, wid = tid >> 6;
  int l15 = lane & 15, lg = lane >> 4;
  int wr = (wid >> 1) * 32, wc = (wid & 1) * 32;
  int col0 = blockIdx.x * 64;
  int sr = tid >> 2, sk = (tid & 3) * 16;
  int gi = ri0 + sr;
  bool av = gi < n;
  int arow = av ? list[e * 1024 + gi] : 0;
  const float* dpe = dp + (size_t)e * 1024 * 1024 + (size_t)(col0 + sr) * 1024 + sk;
  const __hip_bfloat16* Ar = hidden + (size_t)arow * 1024 + sk;
  f32x4 zero4 = {0.f, 0.f, 0.f, 0.f};
  f32x4 acc[2][2];
#pragma unroll
  for (int i = 0; i < 2; i++)
#pragma unroll
    for (int j = 0; j < 2; j++) acc[i][j] = zero4;

  auto d_load = [&](StageD& s, int k) {
    if (av) { s.a0 = *(const short8*)(Ar + k); s.a1 = *(const short8*)(Ar + k + 8); }
    const f32x4* pb = (const f32x4*)(dpe + k);
    s.b0 = pb[0]; s.b1 = pb[1]; s.b2 = pb[2]; s.b3 = pb[3];
  };
  auto d_write = [&](const StageD& s) {
    *(short8*)&As[sr][sk]     = s.a0;
    *(short8*)&As[sr][sk + 8] = s.a1;
    *(short8*)&Bs[sr][sk]     = cvt2(s.b0, s.b1);
    *(short8*)&Bs[sr][sk + 8] = cvt2(s.b2, s.b3);
  };
  auto do_mfma = [&]() {
#pragma unroll
    for (int ks = 0; ks < 2; ks++) {
      short8 af[2], bf[2];
#pragma unroll
      for (int i = 0; i < 2; i++) af[i] = *(const short8*)&As[wr + i * 16 + l15][ks * 32 + lg * 8];
#pragma unroll
      for (int j = 0; j < 2; j++) bf[j] = *(const short8*)&Bs[wc + j * 16 + l15][ks * 32 + lg * 8];
#pragma unroll
      for (int i = 0; i < 2; i++)
#pragma unroll
        for (int j = 0; j < 2; j++)
          acc[i][j] = __builtin_amdgcn_mfma_f32_16x16x32_bf16(af[i], bf[j], acc[i][j], 0, 0, 0);
    }
  };

  StageD s0 = {}, s1 = {};
  d_load(s0, 0);
  d_load(s1, 64);
  for (int k0 = 0; k0 < 1024; k0 += 128) {
    d_write(s0);
    __syncthreads();
    if (k0 + 128 < 1024) d_load(s0, k0 + 128);
    do_mfma();
    __syncthreads();
    d_write(s1);
    __syncthreads();
    if (k0 + 192 < 1024) d_load(s1, k0 + 192);
    do_mfma();
    __syncthreads();
  }
#pragma unroll
  for (int i = 0; i < 2; i++)
#pragma unroll
    for (int r = 0; r < 4; r++) {
      int gi2 = ri0 + wr + i * 16 + lg * 4 + r;
      if (gi2 < n) {
        int s2 = list[e * 1024 + gi2];
        float p = tp[s2];
#pragma unroll
        for (int j = 0; j < 2; j++) {
          int col = col0 + wc + j * 16 + l15;
          dbuf[(size_t)s2 * 1024 + col] = p * acc[i][j][r];
        }
      }
    }
}

__global__ void final_add_k(const float* __restrict__ x2, const float* __restrict__ dbuf,
                            float* __restrict__ out) {
  int s = blockIdx.x, t = threadIdx.x;
  f32x4 a = *(const f32x4*)(x2 + (size_t)s * 1024 + t * 4);
  f32x4 b = *(const f32x4*)(dbuf + (size_t)(2 * s) * 1024 + t * 4);
  f32x4 c = *(const f32x4*)(dbuf + (size_t)(2 * s + 1) * 1024 + t * 4);
  f32x4 o;
#pragma unroll
  for (int r = 0; r < 4; r++) o[r] = a[r] + b[r] + c[r];
  *(f32x4*)(out + (size_t)s * 1024 + t * 4) = o;
}

extern "C" void kernel_launch(void* const* d_in, const int* in_sizes, int n_in,
                              void* d_out, int out_size, void* d_ws, size_t ws_size,
                              hipStream_t stream) {
  const float* x    = (const float*)d_in[0];
  const float* cosb = (const float*)d_in[1];
  const float* sinb = (const float*)d_in[2];
  const float* w_in = (const float*)d_in[5];
  const float* wq   = (const float*)d_in[6];
  const float* wk   = (const float*)d_in[7];
  const float* wv   = (const float*)d_in[8];
  const float* wo   = (const float*)d_in[9];
  const float* w_qn = (const float*)d_in[10];
  const float* w_kn = (const float*)d_in[11];
  const float* w_pn = (const float*)d_in[12];
  const float* wg   = (const float*)d_in[13];
  const float* up   = (const float*)d_in[14];
  const float* gate = (const float*)d_in[15];
  const float* dp   = (const float*)d_in[16];
  float* out = (float*)d_out;

  char* w = (char*)d_ws;
  const size_t MB = 1024 * 1024;
  __hip_bfloat16* hb    = (__hip_bfloat16*)w; w += 2 * MB;
  __hip_bfloat16* woT   = (__hip_bfloat16*)w; w += 2 * MB;
  // ---- dbuf alias region: qb(4) + kbf(1) + vbf(1) + wqT(2) = 8MB ----
  float* qb             = (float*)w;          w += 4 * MB;
  float* kbf            = (float*)w;          w += 1 * MB;
  float* vbf            = (float*)w;          w += 1 * MB;
  __hip_bfloat16* wqT   = (__hip_bfloat16*)w; w += 2 * MB;
  // -------------------------------------------------------------------
  __hip_bfloat16* wkT   = (__hip_bfloat16*)w; w += MB / 2;
  __hip_bfloat16* wvT   = (__hip_bfloat16*)w; w += MB / 2;
  __hip_bfloat16* qb16  = (__hip_bfloat16*)w; w += 2 * MB;
  __hip_bfloat16* kb16  = (__hip_bfloat16*)w; w += MB / 2;
  __hip_bfloat16* vbT   = (__hip_bfloat16*)w; w += MB / 2;
  __hip_bfloat16* attnb = (__hip_bfloat16*)w; w += 2 * MB;
  float* x2             = (float*)w;          w += 4 * MB;
  float* h2f            = (float*)w;          w += 4 * MB;
  __hip_bfloat16* h2b   = (__hip_bfloat16*)w; w += 2 * MB;
  __hip_bfloat16* hidden= (__hip_bfloat16*)w; w += 4 * MB;
  float* tp             = (float*)w;          w += 2048 * 4;
  int* ti               = (int*)w;            w += 2048 * 4;
  int* cnt              = (int*)w;            w += 64 * 4;
  int* list             = (int*)w;            w += 8192 * 4;
  float* dbuf = qb;  // 8MB alias (qb/kbf/vbf/wqT all dead by MoE-down time)

  hipMemsetAsync(cnt, 0, 8 * sizeof(int), stream);

  transpose_cast_k<<<dim3(32, 32), dim3(32, 8), 0, stream>>>(wq, wqT, 1024, 1024);
  transpose_cast_k<<<dim3(8, 32),  dim3(32, 8), 0, stream>>>(wk, wkT, 1024, 256);
  transpose_cast_k<<<dim3(8, 32),  dim3(32, 8), 0, stream>>>(wv, wvT, 1024, 256);
  transpose_cast_k<<<dim3(32, 32), dim3(32, 8), 0, stream>>>(wo, woT, 1024, 1024);

  rmsnorm_b16_k<<<Sq, 256, 0, stream>>>(x, w_in, hb);
  gemm_nt_k<<<dim3(16, 16), 256, 0, stream>>>(hb, wqT, nullptr, qb, 1024, 1024, 1024);
  gemm_nt_k<<<dim3(4, 16),  256, 0, stream>>>(hb, wkT, nullptr, kbf, 1024, 256, 1024);
  gemm_nt_k<<<dim3(4, 16),  256, 0, stream>>>(hb, wvT, nullptr, vbf, 1024, 256, 1024);

  normrope_b16_k<<<Sq, 256, 0, stream>>>(qb, w_qn, cosb, sinb, qb16, 1024);
  normrope_b16_k<<<Sq, 256, 0, stream>>>(kbf, w_kn, cosb, sinb, kb16, 256);
  transpose_cast_k<<<dim3(8, 32), dim3(32, 8), 0, stream>>>(vbf, vbT, 1024, 256);

  attn_flash_k<<<dim3(16, 16), 256, 0, stream>>>(qb16, kb16, vbT, attnb);
  gemm_nt_k<<<dim3(16, 16), 256, 0, stream>>>(attnb, woT, x, x2, 1024, 1024, 1024);

  rmsnorm_dual_k<<<Sq, 256, 0, stream>>>(x2, w_pn, h2f, h2b);
  route_k<<<Sq, 64, 0, stream>>>(h2f, wg, ti, tp);
  scatter_k<<<8, 256, 0, stream>>>(ti, cnt, list);
  moe_upgate_k<<<dim3(16, 16, 8), 256, 0, stream>>>(h2b, up, gate, cnt, list, hidden);
  moe_down_k<<<dim3(16, 16, 8), 256, 0, stream>>>(hidden, dp, cnt, list, tp, dbuf);
  final_add_k<<<Sq, 256, 0, stream>>>(x2, dbuf, out);
}

// Round 7
// 318.625 us; speedup vs baseline: 4.7518x; 1.0715x over previous
//
#include <hip/hip_runtime.h>
#include <hip/hip_bf16.h>

#define Sq 1024
#define Dm 1024
#define Hh 16
#define EPS 1e-5f

typedef __attribute__((ext_vector_type(8))) short short8;
typedef __attribute__((ext_vector_type(4))) short short4v;
typedef __attribute__((ext_vector_type(4))) float f32x4;

static __device__ __forceinline__ short f2bf(float f) {
  __hip_bfloat16 h = __float2bfloat16(f);
  return *reinterpret_cast<short*>(&h);
}

static __device__ __forceinline__ short8 cvt2(f32x4 x, f32x4 y) {
  short8 r;
  r[0] = f2bf(x[0]); r[1] = f2bf(x[1]); r[2] = f2bf(x[2]); r[3] = f2bf(x[3]);
  r[4] = f2bf(y[0]); r[5] = f2bf(y[1]); r[6] = f2bf(y[2]); r[7] = f2bf(y[3]);
  return r;
}

// ------- transpose + cast: in fp32 [R][*lda*] (width Cc) -> out bf16 [Cc][R] -------
__global__ void transpose_cast_k(const float* __restrict__ in, __hip_bfloat16* __restrict__ outT,
                                 int R, int Cc, int lda) {
  __shared__ float t[32][33];
  int c0 = blockIdx.x * 32, r0 = blockIdx.y * 32;
  int tx = threadIdx.x, ty = threadIdx.y;
#pragma unroll
  for (int i = 0; i < 32; i += 8)
    t[ty + i][tx] = in[(size_t)(r0 + ty + i) * lda + c0 + tx];
  __syncthreads();
#pragma unroll
  for (int i = 0; i < 32; i += 8)
    outT[(size_t)(c0 + ty + i) * R + r0 + tx] = __float2bfloat16(t[tx][ty + i]);
}

// ---------------- rmsnorm -> bf16 ----------------
__global__ void rmsnorm_b16_k(const float* __restrict__ in, const float* __restrict__ w,
                              __hip_bfloat16* __restrict__ outb) {
  int s = blockIdx.x, t = threadIdx.x;
  __shared__ float wsum[4];
  f32x4 v = *(const f32x4*)(in + (size_t)s * Dm + t * 4);
  float local = v[0] * v[0] + v[1] * v[1] + v[2] * v[2] + v[3] * v[3];
#pragma unroll
  for (int off = 32; off > 0; off >>= 1) local += __shfl_xor(local, off);
  if ((t & 63) == 0) wsum[t >> 6] = local;
  __syncthreads();
  float scale = rsqrtf((wsum[0] + wsum[1] + wsum[2] + wsum[3]) * (1.f / Dm) + EPS);
  f32x4 wv = *(const f32x4*)(w + t * 4);
  short4v o;
#pragma unroll
  for (int r = 0; r < 4; r++) o[r] = f2bf(v[r] * scale * wv[r]);
  *(short4v*)((unsigned short*)outb + (size_t)s * Dm + t * 4) = o;
}

// ---------------- rmsnorm -> fp32 + bf16 ----------------
__global__ void rmsnorm_dual_k(const float* __restrict__ in, const float* __restrict__ w,
                               float* __restrict__ outf, __hip_bfloat16* __restrict__ outb) {
  int s = blockIdx.x, t = threadIdx.x;
  __shared__ float wsum[4];
  f32x4 v = *(const f32x4*)(in + (size_t)s * Dm + t * 4);
  float local = v[0] * v[0] + v[1] * v[1] + v[2] * v[2] + v[3] * v[3];
#pragma unroll
  for (int off = 32; off > 0; off >>= 1) local += __shfl_xor(local, off);
  if ((t & 63) == 0) wsum[t >> 6] = local;
  __syncthreads();
  float scale = rsqrtf((wsum[0] + wsum[1] + wsum[2] + wsum[3]) * (1.f / Dm) + EPS);
  f32x4 wv = *(const f32x4*)(w + t * 4);
  f32x4 of;
  short4v o;
#pragma unroll
  for (int r = 0; r < 4; r++) { of[r] = v[r] * scale * wv[r]; o[r] = f2bf(of[r]); }
  *(f32x4*)(outf + (size_t)s * Dm + t * 4) = of;
  *(short4v*)((unsigned short*)outb + (size_t)s * Dm + t * 4) = o;
}

// ---------------- fused rmsnorm + RoPE -> bf16 (reads strided input) ----------------
__global__ void normrope_b16_k(const float* __restrict__ in, const float* __restrict__ w,
                               const float* __restrict__ cosb, const float* __restrict__ sinb,
                               __hip_bfloat16* __restrict__ outb, int W, int lda) {
  int s = blockIdx.x, t = threadIdx.x;
  __shared__ float rowb[1024];
  __shared__ float wsum[4];
  const float* row = in + (size_t)s * lda;
  bool act = t * 4 < W;
  f32x4 v = {};
  float local = 0.f;
  if (act) {
    v = *(const f32x4*)(row + t * 4);
    *(f32x4*)&rowb[t * 4] = v;
    local = v[0] * v[0] + v[1] * v[1] + v[2] * v[2] + v[3] * v[3];
  }
#pragma unroll
  for (int off = 32; off > 0; off >>= 1) local += __shfl_xor(local, off);
  if ((t & 63) == 0) wsum[t >> 6] = local;
  __syncthreads();
  if (!act) return;
  float scale = rsqrtf((wsum[0] + wsum[1] + wsum[2] + wsum[3]) / W + EPS);
  int i0 = t * 4, hd = i0 & 63;
  int pair0 = (hd < 32) ? i0 + 32 : i0 - 32;
  f32x4 pv = *(const f32x4*)&rowb[pair0];
  f32x4 wv = *(const f32x4*)(w + i0);
  f32x4 wp = *(const f32x4*)(w + pair0);
  float sgn = (hd < 32) ? -1.f : 1.f;
  short4v o;
#pragma unroll
  for (int r = 0; r < 4; r++) {
    float c = cosb[s * 64 + hd + r], si = sinb[s * 64 + hd + r];
    o[r] = f2bf(v[r] * scale * wv[r] * c + sgn * pv[r] * scale * wp[r] * si);
  }
  *(short4v*)((unsigned short*)outb + (size_t)s * W + i0) = o;
}

// ---------------- dense NT GEMM, 2-deep reg prefetch ----------------
struct StageG { short8 a0, a1, b0, b1; };

__global__ __launch_bounds__(256) void gemm_nt_k(
    const __hip_bfloat16* __restrict__ A, const __hip_bfloat16* __restrict__ Bt,
    const float* __restrict__ add, float* __restrict__ C, int M, int N, int K) {
  __shared__ unsigned short As[64][72];
  __shared__ unsigned short Bs[64][72];
  int tid = threadIdx.x, lane = tid & 63, wid = tid >> 6;
  int l15 = lane & 15, lg = lane >> 4;
  int wr = (wid >> 1) * 32, wc = (wid & 1) * 32;
  int row0 = blockIdx.y * 64, col0 = blockIdx.x * 64;
  int sr = tid >> 2, sk = (tid & 3) * 16;
  const __hip_bfloat16* Ar = A + (size_t)(row0 + sr) * K + sk;
  const __hip_bfloat16* Br = Bt + (size_t)(col0 + sr) * K + sk;
  f32x4 zero4 = {0.f, 0.f, 0.f, 0.f};
  f32x4 acc[2][2];
#pragma unroll
  for (int i = 0; i < 2; i++)
#pragma unroll
    for (int j = 0; j < 2; j++) acc[i][j] = zero4;

  auto g_load = [&](StageG& s, int k) {
    s.a0 = *(const short8*)(Ar + k); s.a1 = *(const short8*)(Ar + k + 8);
    s.b0 = *(const short8*)(Br + k); s.b1 = *(const short8*)(Br + k + 8);
  };
  auto g_write = [&](const StageG& s) {
    *(short8*)&As[sr][sk]     = s.a0;
    *(short8*)&As[sr][sk + 8] = s.a1;
    *(short8*)&Bs[sr][sk]     = s.b0;
    *(short8*)&Bs[sr][sk + 8] = s.b1;
  };
  auto do_mfma = [&]() {
#pragma unroll
    for (int ks = 0; ks < 2; ks++) {
      short8 af[2], bf[2];
#pragma unroll
      for (int i = 0; i < 2; i++) af[i] = *(const short8*)&As[wr + i * 16 + l15][ks * 32 + lg * 8];
#pragma unroll
      for (int j = 0; j < 2; j++) bf[j] = *(const short8*)&Bs[wc + j * 16 + l15][ks * 32 + lg * 8];
#pragma unroll
      for (int i = 0; i < 2; i++)
#pragma unroll
        for (int j = 0; j < 2; j++)
          acc[i][j] = __builtin_amdgcn_mfma_f32_16x16x32_bf16(af[i], bf[j], acc[i][j], 0, 0, 0);
    }
  };

  StageG s0 = {}, s1 = {};
  g_load(s0, 0);
  g_load(s1, 64);
  for (int k0 = 0; k0 < K; k0 += 128) {   // K % 128 == 0
    g_write(s0);
    __syncthreads();
    if (k0 + 128 < K) g_load(s0, k0 + 128);
    do_mfma();
    __syncthreads();
    g_write(s1);
    __syncthreads();
    if (k0 + 192 < K) g_load(s1, k0 + 192);
    do_mfma();
    __syncthreads();
  }
#pragma unroll
  for (int i = 0; i < 2; i++)
#pragma unroll
    for (int r = 0; r < 4; r++) {
      int row = row0 + wr + i * 16 + lg * 4 + r;
#pragma unroll
      for (int j = 0; j < 2; j++) {
        int col = col0 + wc + j * 16 + l15;
        float v = acc[i][j][r];
        if (add) v += add[(size_t)row * N + col];
        C[(size_t)row * N + col] = v;
      }
    }
}

// ---------------- flash attention: block = (64 q-rows, head), 4 waves x 16 rows ----------------
__global__ __launch_bounds__(256) void attn_flash_k(
    const __hip_bfloat16* __restrict__ qb16, const __hip_bfloat16* __restrict__ kb16,
    const __hip_bfloat16* __restrict__ vbT, __hip_bfloat16* __restrict__ attnb) {
  __shared__ unsigned short Kl[32][72];
  __shared__ unsigned short Vt[64][40];
  __shared__ unsigned short Pl[4][16][40];
  int h = blockIdx.y, kvh = h >> 2;
  int q0 = blockIdx.x * 64;
  int tid = threadIdx.x, lane = tid & 63, wid = tid >> 6;
  int l15 = lane & 15, lg = lane >> 4;
  int qr0 = q0 + wid * 16;
  int q_lane = qr0 + l15;

  short8 bq[2];
  const __hip_bfloat16* qrow = qb16 + (size_t)(qr0 + l15) * Dm + h * 64;
  bq[0] = *(const short8*)(qrow + lg * 8);
  bq[1] = *(const short8*)(qrow + 32 + lg * 8);

  f32x4 zero4 = {0.f, 0.f, 0.f, 0.f};
  f32x4 oacc[4];
#pragma unroll
  for (int j = 0; j < 4; j++) oacc[j] = zero4;
  float m_run = -1e30f, lsum = 0.f;

  int nt = q0 / 32 + 2;
  int s_r = tid >> 3, s_off = (tid & 7) * 8;
  int s_dd = tid >> 2, s_c = (tid & 3) * 8;
  for (int t = 0; t < nt; t++) {
    int kv0 = t * 32;
    *(short8*)&Kl[s_r][s_off] = *(const short8*)(kb16 + (size_t)(kv0 + s_r) * 256 + kvh * 64 + s_off);
    *(short8*)&Vt[s_dd][s_c] = *(const short8*)(vbT + (size_t)(kvh * 64 + s_dd) * Sq + kv0 + s_c);
    __syncthreads();

    f32x4 sacc[2];
#pragma unroll
    for (int kvg = 0; kvg < 2; kvg++) {
      short8 ak0 = *(const short8*)&Kl[kvg * 16 + l15][lg * 8];
      short8 ak1 = *(const short8*)&Kl[kvg * 16 + l15][32 + lg * 8];
      f32x4 sa = __builtin_amdgcn_mfma_f32_16x16x32_bf16(ak0, bq[0], zero4, 0, 0, 0);
      sa = __builtin_amdgcn_mfma_f32_16x16x32_bf16(ak1, bq[1], sa, 0, 0, 0);
      sacc[kvg] = sa;
    }
    float s[8];
    float tmax = -1e30f;
#pragma unroll
    for (int kvg = 0; kvg < 2; kvg++)
#pragma unroll
      for (int r = 0; r < 4; r++) {
        int kv_abs = kv0 + kvg * 16 + lg * 4 + r;
        float v = sacc[kvg][r] * 0.125f;
        if (kv_abs > q_lane) v = -1e30f;
        s[kvg * 4 + r] = v;
        tmax = fmaxf(tmax, v);
      }
    tmax = fmaxf(tmax, __shfl_xor(tmax, 16));
    tmax = fmaxf(tmax, __shfl_xor(tmax, 32));
    float m_new = fmaxf(m_run, tmax);
    float corr = __expf(m_run - m_new);
    float psum = 0.f;
#pragma unroll
    for (int i = 0; i < 8; i++) { float p = __expf(s[i] - m_new); s[i] = p; psum += p; }
    psum += __shfl_xor(psum, 16);
    psum += __shfl_xor(psum, 32);
    lsum = lsum * corr + psum;
    m_run = m_new;
    float c4[4];
#pragma unroll
    for (int r = 0; r < 4; r++) c4[r] = __shfl(corr, lg * 4 + r);
#pragma unroll
    for (int j = 0; j < 4; j++)
#pragma unroll
      for (int r = 0; r < 4; r++) oacc[j][r] *= c4[r];
#pragma unroll
    for (int kvg = 0; kvg < 2; kvg++) {
      short4v p4;
#pragma unroll
      for (int r = 0; r < 4; r++) p4[r] = f2bf(s[kvg * 4 + r]);
      *(short4v*)&Pl[wid][l15][kvg * 16 + lg * 4] = p4;
    }
    short8 pa = *(const short8*)&Pl[wid][l15][lg * 8];
#pragma unroll
    for (int j = 0; j < 4; j++) {
      short8 vb = *(const short8*)&Vt[j * 16 + l15][lg * 8];
      oacc[j] = __builtin_amdgcn_mfma_f32_16x16x32_bf16(pa, vb, oacc[j], 0, 0, 0);
    }
    __syncthreads();
  }
  float inv = 1.f / lsum;
  float c4[4];
#pragma unroll
  for (int r = 0; r < 4; r++) c4[r] = __shfl(inv, lg * 4 + r);
#pragma unroll
  for (int j = 0; j < 4; j++)
#pragma unroll
    for (int r = 0; r < 4; r++) {
      int row = qr0 + lg * 4 + r;
      int col = h * 64 + j * 16 + l15;
      attnb[(size_t)row * Dm + col] = __float2bfloat16(oacc[j][r] * c4[r]);
    }
}

// ---------------- routing (fp32) ----------------
__global__ void route_k(const float* __restrict__ h2, const float* __restrict__ wg,
                        int* __restrict__ ti, float* __restrict__ tp) {
  int s = blockIdx.x, lane = threadIdx.x;
  float acc[8] = {0, 0, 0, 0, 0, 0, 0, 0};
  for (int dd = lane; dd < 1024; dd += 64) {
    float hv = h2[(size_t)s * 1024 + dd];
    const float* wr = wg + (size_t)dd * 8;
#pragma unroll
    for (int e = 0; e < 8; e++) acc[e] += hv * wr[e];
  }
#pragma unroll
  for (int off = 32; off > 0; off >>= 1) {
#pragma unroll
    for (int e = 0; e < 8; e++) acc[e] += __shfl_down(acc[e], off);
  }
  if (lane == 0) {
    float m = acc[0];
    for (int e = 1; e < 8; e++) m = fmaxf(m, acc[e]);
    float ex[8], sum = 0.f;
    for (int e = 0; e < 8; e++) { ex[e] = __expf(acc[e] - m); sum += ex[e]; }
    float inv = 1.f / sum;
    int i1 = 0;
    for (int e = 1; e < 8; e++) if (ex[e] > ex[i1]) i1 = e;
    int i2 = (i1 == 0) ? 1 : 0;
    for (int e = 0; e < 8; e++) if (e != i1 && ex[e] > ex[i2]) i2 = e;
    ti[2 * s] = i1; ti[2 * s + 1] = i2;
    tp[2 * s] = ex[i1] * inv; tp[2 * s + 1] = ex[i2] * inv;
  }
}

__global__ void scatter_k(const int* __restrict__ ti, int* __restrict__ cnt,
                          int* __restrict__ list) {
  int t = blockIdx.x * 256 + threadIdx.x;
  if (t < 2048) {
    int e = ti[t];
    int pos = atomicAdd(&cnt[e], 1);
    list[e * 1024 + pos] = t;  // t = s*2 + slot
  }
}

// ------- plan: build compact (expert, row-block) work list; wl[0]=m, wl[1+i]=packed -------
__global__ void plan_k(const int* __restrict__ cnt, int* __restrict__ wl) {
  if (threadIdx.x == 0) {
    int m = 0;
    for (int e = 0; e < 8; e++)
      for (int r = 0; r < cnt[e]; r += 64) { wl[1 + m] = (e << 16) | r; m++; }
    wl[0] = m;
  }
}

// ---------------- MoE up/gate, work-list driven, 2-deep prefetch ----------------
struct StageUG { short8 a0, a1; f32x4 u0, u1, u2, u3, g0, g1, g2, g3; };

__global__ __launch_bounds__(256) void moe_upgate_k(
    const __hip_bfloat16* __restrict__ h2b, const float* __restrict__ up,
    const float* __restrict__ gate, const int* __restrict__ cnt,
    const int* __restrict__ list, const int* __restrict__ wl,
    __hip_bfloat16* __restrict__ hidden) {
  int m = wl[0];
  int widx = blockIdx.y;
  if (widx >= m) return;
  int pk = wl[1 + widx];
  int e = pk >> 16, ri0 = pk & 0xffff;
  int n = cnt[e];
  __shared__ unsigned short As[64][72];
  __shared__ unsigned short Bu[64][72];
  __shared__ unsigned short Bg[64][72];
  int tid = threadIdx.x, lane = tid & 63, wid = tid >> 6;
  int l15 = lane & 15, lg = lane >> 4;
  int wr = (wid >> 1) * 32, wc = (wid & 1) * 32;
  int col0 = blockIdx.x * 64;
  int sr = tid >> 2, sk = (tid & 3) * 16;
  int gi = ri0 + sr;
  bool av = gi < n;
  int arow = av ? (list[e * 1024 + gi] >> 1) : 0;
  const float* upe = up + (size_t)e * 1024 * 1024 + (size_t)(col0 + sr) * 1024 + sk;
  const float* gte = gate + (size_t)e * 1024 * 1024 + (size_t)(col0 + sr) * 1024 + sk;
  const __hip_bfloat16* Ar = h2b + (size_t)arow * 1024 + sk;
  f32x4 zero4 = {0.f, 0.f, 0.f, 0.f};
  f32x4 aU[2][2], aG[2][2];
#pragma unroll
  for (int i = 0; i < 2; i++)
#pragma unroll
    for (int j = 0; j < 2; j++) { aU[i][j] = zero4; aG[i][j] = zero4; }

  auto ug_load = [&](StageUG& s, int k) {
    if (av) { s.a0 = *(const short8*)(Ar + k); s.a1 = *(const short8*)(Ar + k + 8); }
    const f32x4* pu = (const f32x4*)(upe + k);
    const f32x4* pg = (const f32x4*)(gte + k);
    s.u0 = pu[0]; s.u1 = pu[1]; s.u2 = pu[2]; s.u3 = pu[3];
    s.g0 = pg[0]; s.g1 = pg[1]; s.g2 = pg[2]; s.g3 = pg[3];
  };
  auto ug_write = [&](const StageUG& s) {
    *(short8*)&As[sr][sk]     = s.a0;
    *(short8*)&As[sr][sk + 8] = s.a1;
    *(short8*)&Bu[sr][sk]     = cvt2(s.u0, s.u1);
    *(short8*)&Bu[sr][sk + 8] = cvt2(s.u2, s.u3);
    *(short8*)&Bg[sr][sk]     = cvt2(s.g0, s.g1);
    *(short8*)&Bg[sr][sk + 8] = cvt2(s.g2, s.g3);
  };
  auto do_mfma = [&]() {
#pragma unroll
    for (int ks = 0; ks < 2; ks++) {
      short8 af[2], bu[2], bg[2];
#pragma unroll
      for (int i = 0; i < 2; i++) af[i] = *(const short8*)&As[wr + i * 16 + l15][ks * 32 + lg * 8];
#pragma unroll
      for (int j = 0; j < 2; j++) {
        bu[j] = *(const short8*)&Bu[wc + j * 16 + l15][ks * 32 + lg * 8];
        bg[j] = *(const short8*)&Bg[wc + j * 16 + l15][ks * 32 + lg * 8];
      }
#pragma unroll
      for (int i = 0; i < 2; i++)
#pragma unroll
        for (int j = 0; j < 2; j++) {
          aU[i][j] = __builtin_amdgcn_mfma_f32_16x16x32_bf16(af[i], bu[j], aU[i][j], 0, 0, 0);
          aG[i][j] = __builtin_amdgcn_mfma_f32_16x16x32_bf16(af[i], bg[j], aG[i][j], 0, 0, 0);
        }
    }
  };

  StageUG s0 = {}, s1 = {};
  ug_load(s0, 0);
  ug_load(s1, 64);
  for (int k0 = 0; k0 < 1024; k0 += 128) {
    ug_write(s0);
    __syncthreads();
    if (k0 + 128 < 1024) ug_load(s0, k0 + 128);
    do_mfma();
    __syncthreads();
    ug_write(s1);
    __syncthreads();
    if (k0 + 192 < 1024) ug_load(s1, k0 + 192);
    do_mfma();
    __syncthreads();
  }
#pragma unroll
  for (int i = 0; i < 2; i++)
#pragma unroll
    for (int r = 0; r < 4; r++) {
      int gi2 = ri0 + wr + i * 16 + lg * 4 + r;
      if (gi2 < n) {
        int s2 = list[e * 1024 + gi2];
#pragma unroll
        for (int j = 0; j < 2; j++) {
          int col = col0 + wc + j * 16 + l15;
          float g = aG[i][j][r], u = aU[i][j][r];
          float sil = g / (1.f + __expf(-g));
          hidden[(size_t)s2 * 1024 + col] = __float2bfloat16(sil * u);
        }
      }
    }
}

// ---------------- MoE down, work-list driven, 2-deep prefetch ----------------
struct StageD { short8 a0, a1; f32x4 b0, b1, b2, b3; };

__global__ __launch_bounds__(256) void moe_down_k(
    const __hip_bfloat16* __restrict__ hidden, const float* __restrict__ dp,
    const int* __restrict__ cnt, const int* __restrict__ list,
    const float* __restrict__ tp, const int* __restrict__ wl,
    float* __restrict__ dbuf) {
  int m = wl[0];
  int widx = blockIdx.y;
  if (widx >= m) return;
  int pk = wl[1 + widx];
  int e = pk >> 16, ri0 = pk & 0xffff;
  int n = cnt[e];
  __shared__ unsigned short As[64][72];
  __shared__ unsigned short Bs[64][72];
  int tid = threadIdx.x, lane = tid & 63, wid = tid >> 6;
  int l15 = lane & 15, lg = lane >> 4;
  int wr = (wid >> 1) * 32, wc = (wid & 1) * 32;
  int col0 = blockIdx.x * 64;
  int sr = tid >> 2, sk = (tid & 3) * 16;
  int gi = ri0 + sr;
  bool av = gi < n;
  int arow = av ? list[e * 1024 + gi] : 0;
  const float* dpe = dp + (size_t)e * 1024 * 1024 + (size_t)(col0 + sr) * 1024 + sk;
  const __hip_bfloat16* Ar = hidden + (size_t)arow * 1024 + sk;
  f32x4 zero4 = {0.f, 0.f, 0.f, 0.f};
  f32x4 acc[2][2];
#pragma unroll
  for (int i = 0; i < 2; i++)
#pragma unroll
    for (int j = 0; j < 2; j++) acc[i][j] = zero4;

  auto d_load = [&](StageD& s, int k) {
    if (av) { s.a0 = *(const short8*)(Ar + k); s.a1 = *(const short8*)(Ar + k + 8); }
    const f32x4* pb = (const f32x4*)(dpe + k);
    s.b0 = pb[0]; s.b1 = pb[1]; s.b2 = pb[2]; s.b3 = pb[3];
  };
  auto d_write = [&](const StageD& s) {
    *(short8*)&As[sr][sk]     = s.a0;
    *(short8*)&As[sr][sk + 8] = s.a1;
    *(short8*)&Bs[sr][sk]     = cvt2(s.b0, s.b1);
    *(short8*)&Bs[sr][sk + 8] = cvt2(s.b2, s.b3);
  };
  auto do_mfma = [&]() {
#pragma unroll
    for (int ks = 0; ks < 2; ks++) {
      short8 af[2], bf[2];
#pragma unroll
      for (int i = 0; i < 2; i++) af[i] = *(const short8*)&As[wr + i * 16 + l15][ks * 32 + lg * 8];
#pragma unroll
      for (int j = 0; j < 2; j++) bf[j] = *(const short8*)&Bs[wc + j * 16 + l15][ks * 32 + lg * 8];
#pragma unroll
      for (int i = 0; i < 2; i++)
#pragma unroll
        for (int j = 0; j < 2; j++)
          acc[i][j] = __builtin_amdgcn_mfma_f32_16x16x32_bf16(af[i], bf[j], acc[i][j], 0, 0, 0);
    }
  };

  StageD s0 = {}, s1 = {};
  d_load(s0, 0);
  d_load(s1, 64);
  for (int k0 = 0; k0 < 1024; k0 += 128) {
    d_write(s0);
    __syncthreads();
    if (k0 + 128 < 1024) d_load(s0, k0 + 128);
    do_mfma();
    __syncthreads();
    d_write(s1);
    __syncthreads();
    if (k0 + 192 < 1024) d_load(s1, k0 + 192);
    do_mfma();
    __syncthreads();
  }
#pragma unroll
  for (int i = 0; i < 2; i++)
#pragma unroll
    for (int r = 0; r < 4; r++) {
      int gi2 = ri0 + wr + i * 16 + lg * 4 + r;
      if (gi2 < n) {
        int s2 = list[e * 1024 + gi2];
        float p = tp[s2];
#pragma unroll
        for (int j = 0; j < 2; j++) {
          int col = col0 + wc + j * 16 + l15;
          dbuf[(size_t)s2 * 1024 + col] = p * acc[i][j][r];
        }
      }
    }
}

__global__ void final_add_k(const float* __restrict__ x2, const float* __restrict__ dbuf,
                            float* __restrict__ out) {
  int s = blockIdx.x, t = threadIdx.x;
  f32x4 a = *(const f32x4*)(x2 + (size_t)s * 1024 + t * 4);
  f32x4 b = *(const f32x4*)(dbuf + (size_t)(2 * s) * 1024 + t * 4);
  f32x4 c = *(const f32x4*)(dbuf + (size_t)(2 * s + 1) * 1024 + t * 4);
  f32x4 o;
#pragma unroll
  for (int r = 0; r < 4; r++) o[r] = a[r] + b[r] + c[r];
  *(f32x4*)(out + (size_t)s * 1024 + t * 4) = o;
}

extern "C" void kernel_launch(void* const* d_in, const int* in_sizes, int n_in,
                              void* d_out, int out_size, void* d_ws, size_t ws_size,
                              hipStream_t stream) {
  const float* x    = (const float*)d_in[0];
  const float* cosb = (const float*)d_in[1];
  const float* sinb = (const float*)d_in[2];
  const float* w_in = (const float*)d_in[5];
  const float* wq   = (const float*)d_in[6];
  const float* wk   = (const float*)d_in[7];
  const float* wv   = (const float*)d_in[8];
  const float* wo   = (const float*)d_in[9];
  const float* w_qn = (const float*)d_in[10];
  const float* w_kn = (const float*)d_in[11];
  const float* w_pn = (const float*)d_in[12];
  const float* wg   = (const float*)d_in[13];
  const float* up   = (const float*)d_in[14];
  const float* gate = (const float*)d_in[15];
  const float* dp   = (const float*)d_in[16];
  float* out = (float*)d_out;

  char* w = (char*)d_ws;
  const size_t MB = 1024 * 1024;
  __hip_bfloat16* hb     = (__hip_bfloat16*)w; w += 2 * MB;
  __hip_bfloat16* woT    = (__hip_bfloat16*)w; w += 2 * MB;
  // ---- dbuf alias region: qkv fp32 [1024][1536] (6MB) + wqkvT bf16 [1536][1024] (3MB) ----
  float* qkv             = (float*)w;          w += 6 * MB;
  __hip_bfloat16* wqkvT  = (__hip_bfloat16*)w; w += 3 * MB;
  // ------------------------------------------------------------------------------------
  __hip_bfloat16* qb16   = (__hip_bfloat16*)w; w += 2 * MB;
  __hip_bfloat16* kb16   = (__hip_bfloat16*)w; w += MB / 2;
  __hip_bfloat16* vbT    = (__hip_bfloat16*)w; w += MB / 2;
  __hip_bfloat16* attnb  = (__hip_bfloat16*)w; w += 2 * MB;
  float* x2              = (float*)w;          w += 4 * MB;
  float* h2f             = (float*)w;          w += 4 * MB;
  __hip_bfloat16* h2b    = (__hip_bfloat16*)w; w += 2 * MB;
  __hip_bfloat16* hidden = (__hip_bfloat16*)w; w += 4 * MB;
  float* tp              = (float*)w;          w += 2048 * 4;
  int* ti                = (int*)w;            w += 2048 * 4;
  int* cnt               = (int*)w;            w += 64 * 4;
  int* list              = (int*)w;            w += 8192 * 4;
  int* wl                = (int*)w;            w += 64 * 4;
  float* dbuf = qkv;  // 8MB alias (qkv + wqkvT dead by MoE-down time)

  hipMemsetAsync(cnt, 0, 8 * sizeof(int), stream);

  // weights -> bf16 transposed (wq/wk/wv concatenated into wqkvT [1536][1024])
  transpose_cast_k<<<dim3(32, 32), dim3(32, 8), 0, stream>>>(wq, wqkvT, 1024, 1024, 1024);
  transpose_cast_k<<<dim3(8, 32),  dim3(32, 8), 0, stream>>>(wk, wqkvT + (size_t)1024 * 1024, 1024, 256, 256);
  transpose_cast_k<<<dim3(8, 32),  dim3(32, 8), 0, stream>>>(wv, wqkvT + (size_t)1280 * 1024, 1024, 256, 256);
  transpose_cast_k<<<dim3(32, 32), dim3(32, 8), 0, stream>>>(wo, woT, 1024, 1024, 1024);

  rmsnorm_b16_k<<<Sq, 256, 0, stream>>>(x, w_in, hb);
  // fused QKV projection: qkv[1024][1536]
  gemm_nt_k<<<dim3(24, 16), 256, 0, stream>>>(hb, wqkvT, nullptr, qkv, 1024, 1536, 1024);

  normrope_b16_k<<<Sq, 256, 0, stream>>>(qkv, w_qn, cosb, sinb, qb16, 1024, 1536);
  normrope_b16_k<<<Sq, 256, 0, stream>>>(qkv + 1024, w_kn, cosb, sinb, kb16, 256, 1536);
  transpose_cast_k<<<dim3(8, 32), dim3(32, 8), 0, stream>>>(qkv + 1280, vbT, 1024, 256, 1536);

  attn_flash_k<<<dim3(16, 16), 256, 0, stream>>>(qb16, kb16, vbT, attnb);
  gemm_nt_k<<<dim3(16, 16), 256, 0, stream>>>(attnb, woT, x, x2, 1024, 1024, 1024);

  rmsnorm_dual_k<<<Sq, 256, 0, stream>>>(x2, w_pn, h2f, h2b);
  route_k<<<Sq, 64, 0, stream>>>(h2f, wg, ti, tp);
  scatter_k<<<8, 256, 0, stream>>>(ti, cnt, list);
  plan_k<<<1, 64, 0, stream>>>(cnt, wl);
  moe_upgate_k<<<dim3(16, 40), 256, 0, stream>>>(h2b, up, gate, cnt, list, wl, hidden);
  moe_down_k<<<dim3(16, 40), 256, 0, stream>>>(hidden, dp, cnt, list, tp, wl, dbuf);
  final_add_k<<<Sq, 256, 0, stream>>>(x2, dbuf, out);
}

// Round 10
// 306.139 us; speedup vs baseline: 4.9456x; 1.0408x over previous
//
#include <hip/hip_runtime.h>
#include <hip/hip_bf16.h>

#define Sq 1024
#define Dm 1024
#define Hh 16
#define EPS 1e-5f

typedef __attribute__((ext_vector_type(8))) short short8;
typedef __attribute__((ext_vector_type(4))) short short4v;
typedef __attribute__((ext_vector_type(4))) float f32x4;

static __device__ __forceinline__ short f2bf(float f) {
  __hip_bfloat16 h = __float2bfloat16(f);
  return *reinterpret_cast<short*>(&h);
}

static __device__ __forceinline__ short8 cvt2(f32x4 x, f32x4 y) {
  short8 r;
  r[0] = f2bf(x[0]); r[1] = f2bf(x[1]); r[2] = f2bf(x[2]); r[3] = f2bf(x[3]);
  r[4] = f2bf(y[0]); r[5] = f2bf(y[1]); r[6] = f2bf(y[2]); r[7] = f2bf(y[3]);
  return r;
}

// ------- transpose + cast: in fp32 [R][*lda*] (width Cc) -> out bf16 [Cc][R] -------
__global__ void transpose_cast_k(const float* __restrict__ in, __hip_bfloat16* __restrict__ outT,
                                 int R, int Cc, int lda) {
  __shared__ float t[32][33];
  int c0 = blockIdx.x * 32, r0 = blockIdx.y * 32;
  int tx = threadIdx.x, ty = threadIdx.y;
#pragma unroll
  for (int i = 0; i < 32; i += 8)
    t[ty + i][tx] = in[(size_t)(r0 + ty + i) * lda + c0 + tx];
  __syncthreads();
#pragma unroll
  for (int i = 0; i < 32; i += 8)
    outT[(size_t)(c0 + ty + i) * R + r0 + tx] = __float2bfloat16(t[tx][ty + i]);
}

// ---------------- rmsnorm -> bf16 ----------------
__global__ void rmsnorm_b16_k(const float* __restrict__ in, const float* __restrict__ w,
                              __hip_bfloat16* __restrict__ outb) {
  int s = blockIdx.x, t = threadIdx.x;
  __shared__ float wsum[4];
  f32x4 v = *(const f32x4*)(in + (size_t)s * Dm + t * 4);
  float local = v[0] * v[0] + v[1] * v[1] + v[2] * v[2] + v[3] * v[3];
#pragma unroll
  for (int off = 32; off > 0; off >>= 1) local += __shfl_xor(local, off);
  if ((t & 63) == 0) wsum[t >> 6] = local;
  __syncthreads();
  float scale = rsqrtf((wsum[0] + wsum[1] + wsum[2] + wsum[3]) * (1.f / Dm) + EPS);
  f32x4 wv = *(const f32x4*)(w + t * 4);
  short4v o;
#pragma unroll
  for (int r = 0; r < 4; r++) o[r] = f2bf(v[r] * scale * wv[r]);
  *(short4v*)((unsigned short*)outb + (size_t)s * Dm + t * 4) = o;
}

// ---------------- rmsnorm -> fp32 + bf16 ----------------
__global__ void rmsnorm_dual_k(const float* __restrict__ in, const float* __restrict__ w,
                               float* __restrict__ outf, __hip_bfloat16* __restrict__ outb) {
  int s = blockIdx.x, t = threadIdx.x;
  __shared__ float wsum[4];
  f32x4 v = *(const f32x4*)(in + (size_t)s * Dm + t * 4);
  float local = v[0] * v[0] + v[1] * v[1] + v[2] * v[2] + v[3] * v[3];
#pragma unroll
  for (int off = 32; off > 0; off >>= 1) local += __shfl_xor(local, off);
  if ((t & 63) == 0) wsum[t >> 6] = local;
  __syncthreads();
  float scale = rsqrtf((wsum[0] + wsum[1] + wsum[2] + wsum[3]) * (1.f / Dm) + EPS);
  f32x4 wv = *(const f32x4*)(w + t * 4);
  f32x4 of;
  short4v o;
#pragma unroll
  for (int r = 0; r < 4; r++) { of[r] = v[r] * scale * wv[r]; o[r] = f2bf(of[r]); }
  *(f32x4*)(outf + (size_t)s * Dm + t * 4) = of;
  *(short4v*)((unsigned short*)outb + (size_t)s * Dm + t * 4) = o;
}

// ---------------- fused rmsnorm + RoPE -> bf16 (reads strided input) ----------------
__global__ void normrope_b16_k(const float* __restrict__ in, const float* __restrict__ w,
                               const float* __restrict__ cosb, const float* __restrict__ sinb,
                               __hip_bfloat16* __restrict__ outb, int W, int lda) {
  int s = blockIdx.x, t = threadIdx.x;
  __shared__ float rowb[1024];
  __shared__ float wsum[4];
  const float* row = in + (size_t)s * lda;
  bool act = t * 4 < W;
  f32x4 v = {};
  float local = 0.f;
  if (act) {
    v = *(const f32x4*)(row + t * 4);
    *(f32x4*)&rowb[t * 4] = v;
    local = v[0] * v[0] + v[1] * v[1] + v[2] * v[2] + v[3] * v[3];
  }
#pragma unroll
  for (int off = 32; off > 0; off >>= 1) local += __shfl_xor(local, off);
  if ((t & 63) == 0) wsum[t >> 6] = local;
  __syncthreads();
  if (!act) return;
  float scale = rsqrtf((wsum[0] + wsum[1] + wsum[2] + wsum[3]) / W + EPS);
  int i0 = t * 4, hd = i0 & 63;
  int pair0 = (hd < 32) ? i0 + 32 : i0 - 32;
  f32x4 pv = *(const f32x4*)&rowb[pair0];
  f32x4 wv = *(const f32x4*)(w + i0);
  f32x4 wp = *(const f32x4*)(w + pair0);
  float sgn = (hd < 32) ? -1.f : 1.f;
  short4v o;
#pragma unroll
  for (int r = 0; r < 4; r++) {
    float c = cosb[s * 64 + hd + r], si = sinb[s * 64 + hd + r];
    o[r] = f2bf(v[r] * scale * wv[r] * c + sgn * pv[r] * scale * wp[r] * si);
  }
  *(short4v*)((unsigned short*)outb + (size_t)s * W + i0) = o;
}

// ---------------- dense NT GEMM, 2-deep reg prefetch ----------------
struct StageG { short8 a0, a1, b0, b1; };

__global__ __launch_bounds__(256) void gemm_nt_k(
    const __hip_bfloat16* __restrict__ A, const __hip_bfloat16* __restrict__ Bt,
    const float* __restrict__ add, float* __restrict__ C, int M, int N, int K) {
  __shared__ unsigned short As[64][72];
  __shared__ unsigned short Bs[64][72];
  int tid = threadIdx.x, lane = tid & 63, wid = tid >> 6;
  int l15 = lane & 15, lg = lane >> 4;
  int wr = (wid >> 1) * 32, wc = (wid & 1) * 32;
  int row0 = blockIdx.y * 64, col0 = blockIdx.x * 64;
  int sr = tid >> 2, sk = (tid & 3) * 16;
  const __hip_bfloat16* Ar = A + (size_t)(row0 + sr) * K + sk;
  const __hip_bfloat16* Br = Bt + (size_t)(col0 + sr) * K + sk;
  f32x4 zero4 = {0.f, 0.f, 0.f, 0.f};
  f32x4 acc[2][2];
#pragma unroll
  for (int i = 0; i < 2; i++)
#pragma unroll
    for (int j = 0; j < 2; j++) acc[i][j] = zero4;

  auto g_load = [&](StageG& s, int k) {
    s.a0 = *(const short8*)(Ar + k); s.a1 = *(const short8*)(Ar + k + 8);
    s.b0 = *(const short8*)(Br + k); s.b1 = *(const short8*)(Br + k + 8);
  };
  auto g_write = [&](const StageG& s) {
    *(short8*)&As[sr][sk]     = s.a0;
    *(short8*)&As[sr][sk + 8] = s.a1;
    *(short8*)&Bs[sr][sk]     = s.b0;
    *(short8*)&Bs[sr][sk + 8] = s.b1;
  };
  auto do_mfma = [&]() {
#pragma unroll
    for (int ks = 0; ks < 2; ks++) {
      short8 af[2], bf[2];
#pragma unroll
      for (int i = 0; i < 2; i++) af[i] = *(const short8*)&As[wr + i * 16 + l15][ks * 32 + lg * 8];
#pragma unroll
      for (int j = 0; j < 2; j++) bf[j] = *(const short8*)&Bs[wc + j * 16 + l15][ks * 32 + lg * 8];
#pragma unroll
      for (int i = 0; i < 2; i++)
#pragma unroll
        for (int j = 0; j < 2; j++)
          acc[i][j] = __builtin_amdgcn_mfma_f32_16x16x32_bf16(af[i], bf[j], acc[i][j], 0, 0, 0);
    }
  };

  StageG s0 = {}, s1 = {};
  g_load(s0, 0);
  g_load(s1, 64);
  for (int k0 = 0; k0 < K; k0 += 128) {   // K % 128 == 0
    g_write(s0);
    __syncthreads();
    if (k0 + 128 < K) g_load(s0, k0 + 128);
    do_mfma();
    __syncthreads();
    g_write(s1);
    __syncthreads();
    if (k0 + 192 < K) g_load(s1, k0 + 192);
    do_mfma();
    __syncthreads();
  }
#pragma unroll
  for (int i = 0; i < 2; i++)
#pragma unroll
    for (int r = 0; r < 4; r++) {
      int row = row0 + wr + i * 16 + lg * 4 + r;
#pragma unroll
      for (int j = 0; j < 2; j++) {
        int col = col0 + wc + j * 16 + l15;
        float v = acc[i][j][r];
        if (add) v += add[(size_t)row * N + col];
        C[(size_t)row * N + col] = v;
      }
    }
}

// ---------------- flash attention: block = (64 q-rows, head), 4 waves x 16 rows ----------------
__global__ __launch_bounds__(256) void attn_flash_k(
    const __hip_bfloat16* __restrict__ qb16, const __hip_bfloat16* __restrict__ kb16,
    const __hip_bfloat16* __restrict__ vbT, __hip_bfloat16* __restrict__ attnb) {
  __shared__ unsigned short Kl[32][72];
  __shared__ unsigned short Vt[64][40];
  __shared__ unsigned short Pl[4][16][40];
  int h = blockIdx.y, kvh = h >> 2;
  int q0 = blockIdx.x * 64;
  int tid = threadIdx.x, lane = tid & 63, wid = tid >> 6;
  int l15 = lane & 15, lg = lane >> 4;
  int qr0 = q0 + wid * 16;
  int q_lane = qr0 + l15;

  short8 bq[2];
  const __hip_bfloat16* qrow = qb16 + (size_t)(qr0 + l15) * Dm + h * 64;
  bq[0] = *(const short8*)(qrow + lg * 8);
  bq[1] = *(const short8*)(qrow + 32 + lg * 8);

  f32x4 zero4 = {0.f, 0.f, 0.f, 0.f};
  f32x4 oacc[4];
#pragma unroll
  for (int j = 0; j < 4; j++) oacc[j] = zero4;
  float m_run = -1e30f, lsum = 0.f;

  int nt = q0 / 32 + 2;
  int s_r = tid >> 3, s_off = (tid & 7) * 8;
  int s_dd = tid >> 2, s_c = (tid & 3) * 8;
  for (int t = 0; t < nt; t++) {
    int kv0 = t * 32;
    *(short8*)&Kl[s_r][s_off] = *(const short8*)(kb16 + (size_t)(kv0 + s_r) * 256 + kvh * 64 + s_off);
    *(short8*)&Vt[s_dd][s_c] = *(const short8*)(vbT + (size_t)(kvh * 64 + s_dd) * Sq + kv0 + s_c);
    __syncthreads();

    f32x4 sacc[2];
#pragma unroll
    for (int kvg = 0; kvg < 2; kvg++) {
      short8 ak0 = *(const short8*)&Kl[kvg * 16 + l15][lg * 8];
      short8 ak1 = *(const short8*)&Kl[kvg * 16 + l15][32 + lg * 8];
      f32x4 sa = __builtin_amdgcn_mfma_f32_16x16x32_bf16(ak0, bq[0], zero4, 0, 0, 0);
      sa = __builtin_amdgcn_mfma_f32_16x16x32_bf16(ak1, bq[1], sa, 0, 0, 0);
      sacc[kvg] = sa;
    }
    float s[8];
    float tmax = -1e30f;
#pragma unroll
    for (int kvg = 0; kvg < 2; kvg++)
#pragma unroll
      for (int r = 0; r < 4; r++) {
        int kv_abs = kv0 + kvg * 16 + lg * 4 + r;
        float v = sacc[kvg][r] * 0.125f;
        if (kv_abs > q_lane) v = -1e30f;
        s[kvg * 4 + r] = v;
        tmax = fmaxf(tmax, v);
      }
    tmax = fmaxf(tmax, __shfl_xor(tmax, 16));
    tmax = fmaxf(tmax, __shfl_xor(tmax, 32));
    float m_new = fmaxf(m_run, tmax);
    float corr = __expf(m_run - m_new);
    float psum = 0.f;
#pragma unroll
    for (int i = 0; i < 8; i++) { float p = __expf(s[i] - m_new); s[i] = p; psum += p; }
    psum += __shfl_xor(psum, 16);
    psum += __shfl_xor(psum, 32);
    lsum = lsum * corr + psum;
    m_run = m_new;
    float c4[4];
#pragma unroll
    for (int r = 0; r < 4; r++) c4[r] = __shfl(corr, lg * 4 + r);
#pragma unroll
    for (int j = 0; j < 4; j++)
#pragma unroll
      for (int r = 0; r < 4; r++) oacc[j][r] *= c4[r];
#pragma unroll
    for (int kvg = 0; kvg < 2; kvg++) {
      short4v p4;
#pragma unroll
      for (int r = 0; r < 4; r++) p4[r] = f2bf(s[kvg * 4 + r]);
      *(short4v*)&Pl[wid][l15][kvg * 16 + lg * 4] = p4;
    }
    short8 pa = *(const short8*)&Pl[wid][l15][lg * 8];
#pragma unroll
    for (int j = 0; j < 4; j++) {
      short8 vb = *(const short8*)&Vt[j * 16 + l15][lg * 8];
      oacc[j] = __builtin_amdgcn_mfma_f32_16x16x32_bf16(pa, vb, oacc[j], 0, 0, 0);
    }
    __syncthreads();
  }
  float inv = 1.f / lsum;
  float c4[4];
#pragma unroll
  for (int r = 0; r < 4; r++) c4[r] = __shfl(inv, lg * 4 + r);
#pragma unroll
  for (int j = 0; j < 4; j++)
#pragma unroll
    for (int r = 0; r < 4; r++) {
      int row = qr0 + lg * 4 + r;
      int col = h * 64 + j * 16 + l15;
      attnb[(size_t)row * Dm + col] = __float2bfloat16(oacc[j][r] * c4[r]);
    }
}

// ---------------- routing (fp32) ----------------
__global__ void route_k(const float* __restrict__ h2, const float* __restrict__ wg,
                        int* __restrict__ ti, float* __restrict__ tp) {
  int s = blockIdx.x, lane = threadIdx.x;
  float acc[8] = {0, 0, 0, 0, 0, 0, 0, 0};
  for (int dd = lane; dd < 1024; dd += 64) {
    float hv = h2[(size_t)s * 1024 + dd];
    const float* wr = wg + (size_t)dd * 8;
#pragma unroll
    for (int e = 0; e < 8; e++) acc[e] += hv * wr[e];
  }
#pragma unroll
  for (int off = 32; off > 0; off >>= 1) {
#pragma unroll
    for (int e = 0; e < 8; e++) acc[e] += __shfl_down(acc[e], off);
  }
  if (lane == 0) {
    float m = acc[0];
    for (int e = 1; e < 8; e++) m = fmaxf(m, acc[e]);
    float ex[8], sum = 0.f;
    for (int e = 0; e < 8; e++) { ex[e] = __expf(acc[e] - m); sum += ex[e]; }
    float inv = 1.f / sum;
    int i1 = 0;
    for (int e = 1; e < 8; e++) if (ex[e] > ex[i1]) i1 = e;
    int i2 = (i1 == 0) ? 1 : 0;
    for (int e = 0; e < 8; e++) if (e != i1 && ex[e] > ex[i2]) i2 = e;
    ti[2 * s] = i1; ti[2 * s + 1] = i2;
    tp[2 * s] = ex[i1] * inv; tp[2 * s + 1] = ex[i2] * inv;
  }
}

__global__ void scatter_k(const int* __restrict__ ti, int* __restrict__ cnt,
                          int* __restrict__ list) {
  int t = blockIdx.x * 256 + threadIdx.x;
  if (t < 2048) {
    int e = ti[t];
    int pos = atomicAdd(&cnt[e], 1);
    list[e * 1024 + pos] = t;  // t = s*2 + slot
  }
}

// ------- plan: compact (expert, row-block[128]) work list; wl[0]=m, wl[1+i]=packed -------
__global__ void plan_k(const int* __restrict__ cnt, int* __restrict__ wl) {
  if (threadIdx.x == 0) {
    int m = 0;
    for (int e = 0; e < 8; e++)
      for (int r = 0; r < cnt[e]; r += 128) { wl[1 + m] = (e << 16) | r; m++; }
    wl[0] = m;
  }
}

// ---------------- MoE up/gate: M=128 tile, 512 threads (8 waves of 32x32), 2-deep prefetch ----------------
struct StageUG { short8 a0, a1; f32x4 u0, u1, g0, g1; };

__global__ __launch_bounds__(512) void moe_upgate_k(
    const __hip_bfloat16* __restrict__ h2b, const float* __restrict__ up,
    const float* __restrict__ gate, const int* __restrict__ cnt,
    const int* __restrict__ list, const int* __restrict__ wl,
    __hip_bfloat16* __restrict__ hidden) {
  int m = wl[0];
  int widx = blockIdx.y;
  if (widx >= m) return;
  int pk = wl[1 + widx];
  int e = pk >> 16, ri0 = pk & 0xffff;
  int n = cnt[e];
  __shared__ unsigned short As[128][72];   // 18 KB
  __shared__ unsigned short Bu[64][72];    //  9 KB
  __shared__ unsigned short Bg[64][72];    //  9 KB
  int tid = threadIdx.x, lane = tid & 63, wid = tid >> 6;
  int l15 = lane & 15, lg = lane >> 4;
  int wr = (wid >> 1) * 32, wc = (wid & 1) * 32;   // 4 row-groups x 2 col-groups
  int col0 = blockIdx.x * 64;
  // A staging: row = tid>>2 (0..127), k-off = (tid&3)*16
  int sra = tid >> 2, ska = (tid & 3) * 16;
  int gi = ri0 + sra;
  bool av = gi < n;
  int arow = av ? (list[e * 1024 + gi] >> 1) : 0;
  const __hip_bfloat16* Ar = h2b + (size_t)arow * 1024 + ska;
  // weight staging: col = tid>>3 (0..63), k-off = (tid&7)*8
  int sw = tid >> 3, skw = (tid & 7) * 8;
  const float* upe = up + (size_t)e * 1048576 + (size_t)(col0 + sw) * 1024 + skw;
  const float* gte = gate + (size_t)e * 1048576 + (size_t)(col0 + sw) * 1024 + skw;
  f32x4 zero4 = {0.f, 0.f, 0.f, 0.f};
  f32x4 aU[2][2], aG[2][2];
#pragma unroll
  for (int i = 0; i < 2; i++)
#pragma unroll
    for (int j = 0; j < 2; j++) { aU[i][j] = zero4; aG[i][j] = zero4; }

  auto ug_load = [&](StageUG& s, int k) {
    if (av) { s.a0 = *(const short8*)(Ar + k); s.a1 = *(const short8*)(Ar + k + 8); }
    const f32x4* pu = (const f32x4*)(upe + k);
    const f32x4* pg = (const f32x4*)(gte + k);
    s.u0 = pu[0]; s.u1 = pu[1]; s.g0 = pg[0]; s.g1 = pg[1];
  };
  auto ug_write = [&](const StageUG& s) {
    *(short8*)&As[sra][ska]     = s.a0;
    *(short8*)&As[sra][ska + 8] = s.a1;
    *(short8*)&Bu[sw][skw] = cvt2(s.u0, s.u1);
    *(short8*)&Bg[sw][skw] = cvt2(s.g0, s.g1);
  };
  auto do_mfma = [&]() {
#pragma unroll
    for (int ks = 0; ks < 2; ks++) {
      short8 af[2], bu[2], bg[2];
#pragma unroll
      for (int i = 0; i < 2; i++) af[i] = *(const short8*)&As[wr + i * 16 + l15][ks * 32 + lg * 8];
#pragma unroll
      for (int j = 0; j < 2; j++) {
        bu[j] = *(const short8*)&Bu[wc + j * 16 + l15][ks * 32 + lg * 8];
        bg[j] = *(const short8*)&Bg[wc + j * 16 + l15][ks * 32 + lg * 8];
      }
#pragma unroll
      for (int i = 0; i < 2; i++)
#pragma unroll
        for (int j = 0; j < 2; j++) {
          aU[i][j] = __builtin_amdgcn_mfma_f32_16x16x32_bf16(af[i], bu[j], aU[i][j], 0, 0, 0);
          aG[i][j] = __builtin_amdgcn_mfma_f32_16x16x32_bf16(af[i], bg[j], aG[i][j], 0, 0, 0);
        }
    }
  };

  StageUG s0 = {}, s1 = {};
  ug_load(s0, 0);
  ug_load(s1, 64);
  for (int k0 = 0; k0 < 1024; k0 += 128) {
    ug_write(s0);
    __syncthreads();
    if (k0 + 128 < 1024) ug_load(s0, k0 + 128);
    do_mfma();
    __syncthreads();
    ug_write(s1);
    __syncthreads();
    if (k0 + 192 < 1024) ug_load(s1, k0 + 192);
    do_mfma();
    __syncthreads();
  }
  // wave rows: ri0 + wr + i*16 + lg*4 + r ; cols: col0 + wc + j*16 + l15
#pragma unroll
  for (int i = 0; i < 2; i++)
#pragma unroll
    for (int r = 0; r < 4; r++) {
      int gi2 = ri0 + wr + i * 16 + lg * 4 + r;
      if (gi2 < n) {
        int s2 = list[e * 1024 + gi2];
#pragma unroll
        for (int j = 0; j < 2; j++) {
          int col = col0 + wc + j * 16 + l15;
          float g = aG[i][j][r], u = aU[i][j][r];
          float sil = g / (1.f + __expf(-g));
          hidden[(size_t)s2 * 1024 + col] = __float2bfloat16(sil * u);
        }
      }
    }
}

// ---------------- MoE down: M=128 tile, 512 threads, 2-deep prefetch ----------------
struct StageD { short8 a0, a1; f32x4 b0, b1; };

__global__ __launch_bounds__(512) void moe_down_k(
    const __hip_bfloat16* __restrict__ hidden, const float* __restrict__ dp,
    const int* __restrict__ cnt, const int* __restrict__ list,
    const float* __restrict__ tp, const int* __restrict__ wl,
    float* __restrict__ dbuf) {
  int m = wl[0];
  int widx = blockIdx.y;
  if (widx >= m) return;
  int pk = wl[1 + widx];
  int e = pk >> 16, ri0 = pk & 0xffff;
  int n = cnt[e];
  __shared__ unsigned short As[128][72];   // 18 KB
  __shared__ unsigned short Bs[64][72];    //  9 KB
  int tid = threadIdx.x, lane = tid & 63, wid = tid >> 6;
  int l15 = lane & 15, lg = lane >> 4;
  int wr = (wid >> 1) * 32, wc = (wid & 1) * 32;
  int col0 = blockIdx.x * 64;
  int sra = tid >> 2, ska = (tid & 3) * 16;
  int gi = ri0 + sra;
  bool av = gi < n;
  int arow = av ? list[e * 1024 + gi] : 0;
  const __hip_bfloat16* Ar = hidden + (size_t)arow * 1024 + ska;
  int sw = tid >> 3, skw = (tid & 7) * 8;
  const float* dpe = dp + (size_t)e * 1048576 + (size_t)(col0 + sw) * 1024 + skw;
  f32x4 zero4 = {0.f, 0.f, 0.f, 0.f};
  f32x4 acc[2][2];
#pragma unroll
  for (int i = 0; i < 2; i++)
#pragma unroll
    for (int j = 0; j < 2; j++) acc[i][j] = zero4;

  auto d_load = [&](StageD& s, int k) {
    if (av) { s.a0 = *(const short8*)(Ar + k); s.a1 = *(const short8*)(Ar + k + 8); }
    const f32x4* pb = (const f32x4*)(dpe + k);
    s.b0 = pb[0]; s.b1 = pb[1];
  };
  auto d_write = [&](const StageD& s) {
    *(short8*)&As[sra][ska]     = s.a0;
    *(short8*)&As[sra][ska + 8] = s.a1;
    *(short8*)&Bs[sw][skw] = cvt2(s.b0, s.b1);
  };
  auto do_mfma = [&]() {
#pragma unroll
    for (int ks = 0; ks < 2; ks++) {
      short8 af[2], bf[2];
#pragma unroll
      for (int i = 0; i < 2; i++) af[i] = *(const short8*)&As[wr + i * 16 + l15][ks * 32 + lg * 8];
#pragma unroll
      for (int j = 0; j < 2; j++) bf[j] = *(const short8*)&Bs[wc + j * 16 + l15][ks * 32 + lg * 8];
#pragma unroll
      for (int i = 0; i < 2; i++)
#pragma unroll
        for (int j = 0; j < 2; j++)
          acc[i][j] = __builtin_amdgcn_mfma_f32_16x16x32_bf16(af[i], bf[j], acc[i][j], 0, 0, 0);
    }
  };

  StageD s0 = {}, s1 = {};
  d_load(s0, 0);
  d_load(s1, 64);
  for (int k0 = 0; k0 < 1024; k0 += 128) {
    d_write(s0);
    __syncthreads();
    if (k0 + 128 < 1024) d_load(s0, k0 + 128);
    do_mfma();
    __syncthreads();
    d_write(s1);
    __syncthreads();
    if (k0 + 192 < 1024) d_load(s1, k0 + 192);
    do_mfma();
    __syncthreads();
  }
#pragma unroll
  for (int i = 0; i < 2; i++)
#pragma unroll
    for (int r = 0; r < 4; r++) {
      int gi2 = ri0 + wr + i * 16 + lg * 4 + r;
      if (gi2 < n) {
        int s2 = list[e * 1024 + gi2];
        float p = tp[s2];
#pragma unroll
        for (int j = 0; j < 2; j++) {
          int col = col0 + wc + j * 16 + l15;
          dbuf[(size_t)s2 * 1024 + col] = p * acc[i][j][r];
        }
      }
    }
}

__global__ void final_add_k(const float* __restrict__ x2, const float* __restrict__ dbuf,
                            float* __restrict__ out) {
  int s = blockIdx.x, t = threadIdx.x;
  f32x4 a = *(const f32x4*)(x2 + (size_t)s * 1024 + t * 4);
  f32x4 b = *(const f32x4*)(dbuf + (size_t)(2 * s) * 1024 + t * 4);
  f32x4 c = *(const f32x4*)(dbuf + (size_t)(2 * s + 1) * 1024 + t * 4);
  f32x4 o;
#pragma unroll
  for (int r = 0; r < 4; r++) o[r] = a[r] + b[r] + c[r];
  *(f32x4*)(out + (size_t)s * 1024 + t * 4) = o;
}

extern "C" void kernel_launch(void* const* d_in, const int* in_sizes, int n_in,
                              void* d_out, int out_size, void* d_ws, size_t ws_size,
                              hipStream_t stream) {
  const float* x    = (const float*)d_in[0];
  const float* cosb = (const float*)d_in[1];
  const float* sinb = (const float*)d_in[2];
  const float* w_in = (const float*)d_in[5];
  const float* wq   = (const float*)d_in[6];
  const float* wk   = (const float*)d_in[7];
  const float* wv   = (const float*)d_in[8];
  const float* wo   = (const float*)d_in[9];
  const float* w_qn = (const float*)d_in[10];
  const float* w_kn = (const float*)d_in[11];
  const float* w_pn = (const float*)d_in[12];
  const float* wg   = (const float*)d_in[13];
  const float* up   = (const float*)d_in[14];
  const float* gate = (const float*)d_in[15];
  const float* dp   = (const float*)d_in[16];
  float* out = (float*)d_out;

  char* w = (char*)d_ws;
  const size_t MB = 1024 * 1024;
  __hip_bfloat16* hb     = (__hip_bfloat16*)w; w += 2 * MB;
  __hip_bfloat16* woT    = (__hip_bfloat16*)w; w += 2 * MB;
  // ---- dbuf alias region: qkv fp32 [1024][1536] (6MB) + wqkvT bf16 [1536][1024] (3MB) ----
  float* qkv             = (float*)w;          w += 6 * MB;
  __hip_bfloat16* wqkvT  = (__hip_bfloat16*)w; w += 3 * MB;
  // ------------------------------------------------------------------------------------
  __hip_bfloat16* qb16   = (__hip_bfloat16*)w; w += 2 * MB;
  __hip_bfloat16* kb16   = (__hip_bfloat16*)w; w += MB / 2;
  __hip_bfloat16* vbT    = (__hip_bfloat16*)w; w += MB / 2;
  __hip_bfloat16* attnb  = (__hip_bfloat16*)w; w += 2 * MB;
  float* x2              = (float*)w;          w += 4 * MB;
  float* h2f             = (float*)w;          w += 4 * MB;
  __hip_bfloat16* h2b    = (__hip_bfloat16*)w; w += 2 * MB;
  __hip_bfloat16* hidden = (__hip_bfloat16*)w; w += 4 * MB;
  float* tp              = (float*)w;          w += 2048 * 4;
  int* ti                = (int*)w;            w += 2048 * 4;
  int* cnt               = (int*)w;            w += 64 * 4;
  int* list              = (int*)w;            w += 8192 * 4;
  int* wl                = (int*)w;            w += 64 * 4;
  float* dbuf = qkv;  // 8MB alias (qkv + wqkvT dead by MoE-down time)

  hipMemsetAsync(cnt, 0, 8 * sizeof(int), stream);

  // weights -> bf16 transposed (wq/wk/wv concatenated into wqkvT [1536][1024])
  transpose_cast_k<<<dim3(32, 32), dim3(32, 8), 0, stream>>>(wq, wqkvT, 1024, 1024, 1024);
  transpose_cast_k<<<dim3(8, 32),  dim3(32, 8), 0, stream>>>(wk, wqkvT + (size_t)1024 * 1024, 1024, 256, 256);
  transpose_cast_k<<<dim3(8, 32),  dim3(32, 8), 0, stream>>>(wv, wqkvT + (size_t)1280 * 1024, 1024, 256, 256);
  transpose_cast_k<<<dim3(32, 32), dim3(32, 8), 0, stream>>>(wo, woT, 1024, 1024, 1024);

  rmsnorm_b16_k<<<Sq, 256, 0, stream>>>(x, w_in, hb);
  // fused QKV projection: qkv[1024][1536]
  gemm_nt_k<<<dim3(24, 16), 256, 0, stream>>>(hb, wqkvT, nullptr, qkv, 1024, 1536, 1024);

  normrope_b16_k<<<Sq, 256, 0, stream>>>(qkv, w_qn, cosb, sinb, qb16, 1024, 1536);
  normrope_b16_k<<<Sq, 256, 0, stream>>>(qkv + 1024, w_kn, cosb, sinb, kb16, 256, 1536);
  transpose_cast_k<<<dim3(8, 32), dim3(32, 8), 0, stream>>>(qkv + 1280, vbT, 1024, 256, 1536);

  attn_flash_k<<<dim3(16, 16), 256, 0, stream>>>(qb16, kb16, vbT, attnb);
  gemm_nt_k<<<dim3(16, 16), 256, 0, stream>>>(attnb, woT, x, x2, 1024, 1024, 1024);

  rmsnorm_dual_k<<<Sq, 256, 0, stream>>>(x2, w_pn, h2f, h2b);
  route_k<<<Sq, 64, 0, stream>>>(h2f, wg, ti, tp);
  scatter_k<<<8, 256, 0, stream>>>(ti, cnt, list);
  plan_k<<<1, 64, 0, stream>>>(cnt, wl);
  // worst-case wl entries: 8 experts + 2048/128 = 24
  moe_upgate_k<<<dim3(16, 24), 512, 0, stream>>>(h2b, up, gate, cnt, list, wl, hidden);
  moe_down_k<<<dim3(16, 24), 512, 0, stream>>>(hidden, dp, cnt, list, tp, wl, dbuf);
  final_add_k<<<Sq, 256, 0, stream>>>(x2, dbuf, out);
}